// Round 1
// baseline (2479.987 us; speedup 1.0000x reference)
//
#include <hip/hip_runtime.h>
#include <hip/hip_bf16.h>
#include <math.h>

#define H_DIM   2048
#define NH      16
#define NKV     4
#define HD      128
#define NE      16
#define TOPK    4
#define DFF     1024
#define NG      4
#define TG      2
#define SEQ     1024
#define QKV_N   3072          // (NH + 2*NKV)*HD
#define EPS_RMS 1e-6f
#define THETA   1000000.0f

// ---------------------------------------------------------------- RMSNorm
__global__ __launch_bounds__(256) void rmsnorm_kernel(const float* __restrict__ in,
                                                      const float* __restrict__ w,
                                                      float* __restrict__ out) {
    int t = blockIdx.x;
    const float* xt = in + (size_t)t * H_DIM;
    float ss = 0.f;
    for (int d = threadIdx.x * 4; d < H_DIM; d += 1024) {
        float4 v = *reinterpret_cast<const float4*>(xt + d);
        ss += v.x * v.x + v.y * v.y + v.z * v.z + v.w * v.w;
    }
    for (int off = 1; off < 64; off <<= 1) ss += __shfl_xor(ss, off);
    __shared__ float red[4];
    __shared__ float srms;
    if ((threadIdx.x & 63) == 0) red[threadIdx.x >> 6] = ss;
    __syncthreads();
    if (threadIdx.x == 0)
        srms = rsqrtf((red[0] + red[1] + red[2] + red[3]) * (1.f / H_DIM) + EPS_RMS);
    __syncthreads();
    float r = srms;
    for (int d = threadIdx.x * 4; d < H_DIM; d += 1024) {
        float4 v  = *reinterpret_cast<const float4*>(xt + d);
        float4 wv = *reinterpret_cast<const float4*>(w + d);
        float4 ov;
        ov.x = v.x * r * wv.x; ov.y = v.y * r * wv.y;
        ov.z = v.z * r * wv.z; ov.w = v.w * r * wv.w;
        *reinterpret_cast<float4*>(out + (size_t)t * H_DIM + d) = ov;
    }
}

// ---------------------------------------------------------------- generic f32 GEMM
// C[M,N] = A[M,K] @ B[K,N] (+R), optionally duplicated into C2.
__global__ __launch_bounds__(256) void gemm_f32(const float* __restrict__ A,
                                                const float* __restrict__ B,
                                                float* __restrict__ C,
                                                float* __restrict__ C2,
                                                const float* __restrict__ R,
                                                int M, int N, int K) {
    __shared__ float As[64][17];
    __shared__ float Bs[16][64];
    int row0 = blockIdx.y * 64, col0 = blockIdx.x * 64;
    int tid = threadIdx.x, tx = tid & 15, ty = tid >> 4;
    float acc[4][4] = {};
    for (int k0 = 0; k0 < K; k0 += 16) {
        {
            int r = tid >> 2, kk = (tid & 3) * 4;
            float4 v = *reinterpret_cast<const float4*>(&A[(size_t)(row0 + r) * K + k0 + kk]);
            As[r][kk] = v.x; As[r][kk + 1] = v.y; As[r][kk + 2] = v.z; As[r][kk + 3] = v.w;
        }
        {
            int kk = tid >> 6, c = tid & 63;
            #pragma unroll
            for (int i = 0; i < 4; i++)
                Bs[kk + 4 * i][c] = B[(size_t)(k0 + kk + 4 * i) * N + col0 + c];
        }
        __syncthreads();
        #pragma unroll
        for (int kk = 0; kk < 16; kk++) {
            float a[4], b[4];
            #pragma unroll
            for (int i = 0; i < 4; i++) a[i] = As[ty * 4 + i][kk];
            #pragma unroll
            for (int j = 0; j < 4; j++) b[j] = Bs[kk][tx * 4 + j];
            #pragma unroll
            for (int i = 0; i < 4; i++)
                #pragma unroll
                for (int j = 0; j < 4; j++) acc[i][j] += a[i] * b[j];
        }
        __syncthreads();
    }
    for (int i = 0; i < 4; i++) {
        int r = row0 + ty * 4 + i;
        for (int j = 0; j < 4; j++) {
            int c = col0 + tx * 4 + j;
            float v = acc[i][j];
            if (R)  v += R[(size_t)r * N + c];
            C[(size_t)r * N + c] = v;
            if (C2) C2[(size_t)r * N + c] = v;
        }
    }
}

// ---------------------------------------------------------------- RoPE (NEOX style, in place on qkv)
__global__ void rope_kernel(float* __restrict__ qkv, const int* __restrict__ positions) {
    int t = blockIdx.x;
    int h = blockIdx.y;             // 0..15 q heads, 16..19 k heads
    int i = threadIdx.x;            // 0..63
    float pos = (float)positions[t];
    float inv = powf(THETA, -(float)i / 64.0f);
    float ang = pos * inv;
    float s, c;
    sincosf(ang, &s, &c);
    size_t base = (size_t)t * QKV_N + (h < NH ? h * HD : NH * HD + (h - NH) * HD);
    float x1 = qkv[base + i], x2 = qkv[base + 64 + i];
    qkv[base + i]      = x1 * c - x2 * s;
    qkv[base + 64 + i] = x2 * c + x1 * s;
}

// ---------------------------------------------------------------- causal GQA attention
__global__ __launch_bounds__(128) void attn_kernel(const float* __restrict__ qkv,
                                                   float* __restrict__ o) {
    int t = blockIdx.x;             // query token
    int h = blockIdx.y;             // q head
    int tid = threadIdx.x;          // 128
    int kvh = h >> 2;               // NH/NKV = 4
    __shared__ float qs[HD];
    __shared__ float sc[SEQ];
    __shared__ float wred[2], wred2[2];
    const float scale = 0.08838834764831845f;   // 128^-0.5
    qs[tid] = qkv[(size_t)t * QKV_N + h * HD + tid] * scale;
    __syncthreads();
    int L = t + 1;
    for (int j = tid; j < L; j += 128) {
        const float* kp = qkv + (size_t)j * QKV_N + NH * HD + kvh * HD;
        float s = 0.f;
        #pragma unroll
        for (int d = 0; d < HD; d += 4) {
            float4 kv = *reinterpret_cast<const float4*>(kp + d);
            s += qs[d] * kv.x + qs[d + 1] * kv.y + qs[d + 2] * kv.z + qs[d + 3] * kv.w;
        }
        sc[j] = s;
    }
    __syncthreads();
    float m = -1e30f;
    for (int j = tid; j < L; j += 128) m = fmaxf(m, sc[j]);
    for (int off = 1; off < 64; off <<= 1) m = fmaxf(m, __shfl_xor(m, off));
    if ((tid & 63) == 0) wred[tid >> 6] = m;
    __syncthreads();
    m = fmaxf(wred[0], wred[1]);
    float sum = 0.f;
    for (int j = tid; j < L; j += 128) {
        float p = expf(sc[j] - m);
        sc[j] = p;
        sum += p;
    }
    for (int off = 1; off < 64; off <<= 1) sum += __shfl_xor(sum, off);
    if ((tid & 63) == 0) wred2[tid >> 6] = sum;
    __syncthreads();
    float inv = 1.0f / (wred2[0] + wred2[1]);
    float acc = 0.f;
    const float* vb = qkv + (NH + NKV) * HD + kvh * HD + tid;
    for (int j = 0; j < L; j++) acc += sc[j] * vb[(size_t)j * QKV_N];
    o[(size_t)t * H_DIM + h * HD + tid] = acc * inv;
}

// ---------------------------------------------------------------- router
__global__ __launch_bounds__(256) void router_kernel(const float* __restrict__ x,
                                                     const float* __restrict__ gate_w,
                                                     const float* __restrict__ gate_bias,
                                                     int* __restrict__ toklist,
                                                     float* __restrict__ tokw,
                                                     int* __restrict__ cnt) {
    int t = blockIdx.x;
    const float* xt = x + (size_t)t * H_DIM;
    __shared__ float logits[NE];
    __shared__ float red[4];
    for (int e = 0; e < NE; e++) {
        float p = 0.f;
        for (int d = threadIdx.x; d < H_DIM; d += 256) p += xt[d] * gate_w[(size_t)e * H_DIM + d];
        for (int off = 1; off < 64; off <<= 1) p += __shfl_xor(p, off);
        if ((threadIdx.x & 63) == 0) red[threadIdx.x >> 6] = p;
        __syncthreads();
        if (threadIdx.x == 0) logits[e] = red[0] + red[1] + red[2] + red[3];
        __syncthreads();
    }
    if (threadIdx.x == 0) {
        float sig[NE], sb[NE];
        for (int e = 0; e < NE; e++) {
            sig[e] = 1.f / (1.f + expf(-logits[e]));
            sb[e] = sig[e] + gate_bias[e];
        }
        float gs[NG];
        for (int g = 0; g < NG; g++) {
            float m1 = -1e30f, m2 = -1e30f;
            for (int i = 0; i < 4; i++) {
                float v = sb[g * 4 + i];
                if (v > m1) { m2 = m1; m1 = v; } else if (v > m2) m2 = v;
            }
            gs[g] = m1 + m2;
        }
        int g1 = 0;
        for (int g = 1; g < NG; g++) if (gs[g] > gs[g1]) g1 = g;
        int g2 = -1;
        for (int g = 0; g < NG; g++) {
            if (g == g1) continue;
            if (g2 < 0 || gs[g] > gs[g2]) g2 = g;
        }
        bool allowed[NE], used[NE];
        for (int e = 0; e < NE; e++) { int g = e >> 2; allowed[e] = (g == g1 || g == g2); used[e] = false; }
        int sel[TOPK]; float wsel[TOPK]; float wsum = 0.f;
        for (int k = 0; k < TOPK; k++) {
            int best = -1; float bv = -1e30f;
            for (int e = 0; e < NE; e++) {
                if (!allowed[e] || used[e]) continue;
                if (best < 0 || sb[e] > bv) { best = e; bv = sb[e]; }
            }
            used[best] = true; sel[k] = best; wsel[k] = sig[best]; wsum += sig[best];
        }
        float invs = 1.f / (wsum + 1e-20f);
        for (int k = 0; k < TOPK; k++) {
            int e = sel[k];
            int slot = atomicAdd(&cnt[e], 1);
            toklist[e * SEQ + slot] = t;
            tokw[e * SEQ + slot] = wsel[k] * invs;
        }
    }
}

__global__ void prefix_kernel(const int* __restrict__ cnt, int* __restrict__ base) {
    if (threadIdx.x == 0) {
        int s = 0;
        for (int e = 0; e < NE; e++) { base[e] = s; s += cnt[e]; }
    }
}

// ---------------------------------------------------------------- MoE GEMM1: gathered x @ gate_up -> silu(g)*u
__global__ __launch_bounds__(256) void moe_gemm1(const float* __restrict__ x,
                                                 const float* __restrict__ gup,
                                                 const int* __restrict__ toklist,
                                                 const int* __restrict__ cnt,
                                                 const int* __restrict__ base,
                                                 float* __restrict__ act) {
    int e = blockIdx.z;
    int ce = cnt[e];
    int t0 = blockIdx.y * 64;
    if (t0 >= ce) return;
    int f0 = blockIdx.x * 64;
    __shared__ float Xs[64][17];
    __shared__ float Gs[16][64];
    __shared__ float Us[16][64];
    __shared__ int toks[64];
    int tid = threadIdx.x, tx = tid & 15, ty = tid >> 4;
    if (tid < 64) toks[tid] = (t0 + tid < ce) ? toklist[e * SEQ + t0 + tid] : toklist[e * SEQ + t0];
    __syncthreads();
    float accG[4][4] = {}, accU[4][4] = {};
    const float* W = gup + (size_t)e * H_DIM * (2 * DFF);
    for (int k0 = 0; k0 < H_DIM; k0 += 16) {
        {
            int r = tid >> 2, kk = (tid & 3) * 4;
            float4 v = *reinterpret_cast<const float4*>(&x[(size_t)toks[r] * H_DIM + k0 + kk]);
            Xs[r][kk] = v.x; Xs[r][kk + 1] = v.y; Xs[r][kk + 2] = v.z; Xs[r][kk + 3] = v.w;
        }
        {
            int kk = tid >> 6, c = tid & 63;
            #pragma unroll
            for (int i = 0; i < 4; i++) {
                const float* wr = W + (size_t)(k0 + kk + 4 * i) * (2 * DFF);
                Gs[kk + 4 * i][c] = wr[f0 + c];
                Us[kk + 4 * i][c] = wr[DFF + f0 + c];
            }
        }
        __syncthreads();
        #pragma unroll
        for (int kk = 0; kk < 16; kk++) {
            float a[4], bg[4], bu[4];
            #pragma unroll
            for (int i = 0; i < 4; i++) a[i] = Xs[ty * 4 + i][kk];
            #pragma unroll
            for (int j = 0; j < 4; j++) { bg[j] = Gs[kk][tx * 4 + j]; bu[j] = Us[kk][tx * 4 + j]; }
            #pragma unroll
            for (int i = 0; i < 4; i++)
                #pragma unroll
                for (int j = 0; j < 4; j++) { accG[i][j] += a[i] * bg[j]; accU[i][j] += a[i] * bu[j]; }
        }
        __syncthreads();
    }
    int b = base[e];
    for (int i = 0; i < 4; i++) {
        int slot = t0 + ty * 4 + i;
        if (slot >= ce) break;
        float* arow = act + (size_t)(b + slot) * DFF + f0;
        for (int j = 0; j < 4; j++) {
            float g = accG[i][j], u = accU[i][j];
            arow[tx * 4 + j] = (g / (1.f + expf(-g))) * u;
        }
    }
}

// ---------------------------------------------------------------- MoE GEMM2: act @ down -> scatter-add into out
__global__ __launch_bounds__(256) void moe_gemm2(const float* __restrict__ act,
                                                 const float* __restrict__ down,
                                                 const int* __restrict__ toklist,
                                                 const float* __restrict__ tokw,
                                                 const int* __restrict__ cnt,
                                                 const int* __restrict__ base,
                                                 float* __restrict__ out) {
    int e = blockIdx.z;
    int ce = cnt[e];
    int t0 = blockIdx.y * 64;
    if (t0 >= ce) return;
    int c0 = blockIdx.x * 64;
    __shared__ float As[64][17];
    __shared__ float Bs[16][64];
    int tid = threadIdx.x, tx = tid & 15, ty = tid >> 4;
    int b = base[e];
    float acc[4][4] = {};
    const float* W = down + (size_t)e * DFF * H_DIM;
    for (int k0 = 0; k0 < DFF; k0 += 16) {
        {
            int r = tid >> 2, kk = (tid & 3) * 4;
            int slot = (t0 + r < ce) ? (t0 + r) : t0;
            float4 v = *reinterpret_cast<const float4*>(&act[(size_t)(b + slot) * DFF + k0 + kk]);
            As[r][kk] = v.x; As[r][kk + 1] = v.y; As[r][kk + 2] = v.z; As[r][kk + 3] = v.w;
        }
        {
            int kk = tid >> 6, c = tid & 63;
            #pragma unroll
            for (int i = 0; i < 4; i++)
                Bs[kk + 4 * i][c] = W[(size_t)(k0 + kk + 4 * i) * H_DIM + c0 + c];
        }
        __syncthreads();
        #pragma unroll
        for (int kk = 0; kk < 16; kk++) {
            float a[4], bb[4];
            #pragma unroll
            for (int i = 0; i < 4; i++) a[i] = As[ty * 4 + i][kk];
            #pragma unroll
            for (int j = 0; j < 4; j++) bb[j] = Bs[kk][tx * 4 + j];
            #pragma unroll
            for (int i = 0; i < 4; i++)
                #pragma unroll
                for (int j = 0; j < 4; j++) acc[i][j] += a[i] * bb[j];
        }
        __syncthreads();
    }
    for (int i = 0; i < 4; i++) {
        int slot = t0 + ty * 4 + i;
        if (slot >= ce) break;
        int tok = toklist[e * SEQ + slot];
        float w = tokw[e * SEQ + slot];
        for (int j = 0; j < 4; j++)
            atomicAdd(&out[(size_t)tok * H_DIM + c0 + tx * 4 + j], w * acc[i][j]);
    }
}

// ---------------------------------------------------------------- launch
extern "C" void kernel_launch(void* const* d_in, const int* in_sizes, int n_in,
                              void* d_out, int out_size, void* d_ws, size_t ws_size,
                              hipStream_t stream) {
    const float* hidden     = (const float*)d_in[0];
    const int*   positions  = (const int*)d_in[1];
    const float* in_norm_w  = (const float*)d_in[2];
    const float* post_norm_w= (const float*)d_in[3];
    const float* qkv_w      = (const float*)d_in[4];
    const float* o_w        = (const float*)d_in[5];
    const float* gate_w     = (const float*)d_in[6];
    const float* gate_bias  = (const float*)d_in[7];
    const float* gate_up_w  = (const float*)d_in[8];
    const float* down_w     = (const float*)d_in[9];
    float* out = (float*)d_out;

    float* ws   = (float*)d_ws;
    float* h    = ws;                         // 1024*2048
    float* qkv  = h    + (size_t)SEQ * H_DIM; // 1024*3072
    float* o    = qkv  + (size_t)SEQ * QKV_N; // 1024*2048
    float* h2   = o    + (size_t)SEQ * H_DIM; // 1024*2048
    float* x    = h2   + (size_t)SEQ * H_DIM; // 1024*2048
    float* act  = x    + (size_t)SEQ * H_DIM; // 4096*1024
    float* tokw = act  + (size_t)4 * SEQ * DFF;          // 16*1024
    int* toklist = (int*)(tokw + NE * SEQ);   // 16*1024
    int* cnt  = toklist + NE * SEQ;           // 16
    int* base = cnt + NE;                     // 16

    // 1. pre-attention RMSNorm
    rmsnorm_kernel<<<SEQ, 256, 0, stream>>>(hidden, in_norm_w, h);
    // 2. qkv projection
    gemm_f32<<<dim3(QKV_N / 64, SEQ / 64), 256, 0, stream>>>(h, qkv_w, qkv, nullptr, nullptr,
                                                             SEQ, QKV_N, H_DIM);
    // 3. RoPE on q and k heads
    rope_kernel<<<dim3(SEQ, NH + NKV), 64, 0, stream>>>(qkv, positions);
    // 4. attention
    attn_kernel<<<dim3(SEQ, NH), 128, 0, stream>>>(qkv, o);
    // 5. o projection + residual -> h2 (ws) and d_out
    gemm_f32<<<dim3(H_DIM / 64, SEQ / 64), 256, 0, stream>>>(o, o_w, h2, out, hidden,
                                                             SEQ, H_DIM, H_DIM);
    // 6. post-attention RMSNorm
    rmsnorm_kernel<<<SEQ, 256, 0, stream>>>(h2, post_norm_w, x);
    // 7. router
    hipMemsetAsync(cnt, 0, NE * sizeof(int), stream);
    router_kernel<<<SEQ, 256, 0, stream>>>(x, gate_w, gate_bias, toklist, tokw, cnt);
    prefix_kernel<<<1, 64, 0, stream>>>(cnt, base);
    // 8. MoE
    moe_gemm1<<<dim3(DFF / 64, SEQ / 64, NE), 256, 0, stream>>>(x, gate_up_w, toklist, cnt, base, act);
    moe_gemm2<<<dim3(H_DIM / 64, SEQ / 64, NE), 256, 0, stream>>>(act, down_w, toklist, tokw, cnt, base, out);
}

// Round 2
// 1420.301 us; speedup vs baseline: 1.7461x; 1.7461x over previous
//
#include <hip/hip_runtime.h>
#include <hip/hip_bf16.h>
#include <math.h>

#define H_DIM   2048
#define NH      16
#define NKV     4
#define HD      128
#define NE      16
#define TOPK    4
#define DFF     1024
#define NG      4
#define TG      2
#define SEQ     1024
#define QKV_N   3072          // (NH + 2*NKV)*HD
#define EPS_RMS 1e-6f
#define THETA   1000000.0f

typedef __attribute__((ext_vector_type(8))) short bf16x8;
typedef __attribute__((ext_vector_type(4))) float f32x4;

__device__ inline unsigned short f2bf(float x) {
    unsigned u = __builtin_bit_cast(unsigned, x);
    unsigned r = (u + 0x7FFFu + ((u >> 16) & 1u)) >> 16;
    return (unsigned short)r;
}

// ---------------------------------------------------------------- RMSNorm
__global__ __launch_bounds__(256) void rmsnorm_kernel(const float* __restrict__ in,
                                                      const float* __restrict__ w,
                                                      float* __restrict__ out) {
    int t = blockIdx.x;
    const float* xt = in + (size_t)t * H_DIM;
    float ss = 0.f;
    for (int d = threadIdx.x * 4; d < H_DIM; d += 1024) {
        float4 v = *reinterpret_cast<const float4*>(xt + d);
        ss += v.x * v.x + v.y * v.y + v.z * v.z + v.w * v.w;
    }
    for (int off = 1; off < 64; off <<= 1) ss += __shfl_xor(ss, off);
    __shared__ float red[4];
    __shared__ float srms;
    if ((threadIdx.x & 63) == 0) red[threadIdx.x >> 6] = ss;
    __syncthreads();
    if (threadIdx.x == 0)
        srms = rsqrtf((red[0] + red[1] + red[2] + red[3]) * (1.f / H_DIM) + EPS_RMS);
    __syncthreads();
    float r = srms;
    for (int d = threadIdx.x * 4; d < H_DIM; d += 1024) {
        float4 v  = *reinterpret_cast<const float4*>(xt + d);
        float4 wv = *reinterpret_cast<const float4*>(w + d);
        float4 ov;
        ov.x = v.x * r * wv.x; ov.y = v.y * r * wv.y;
        ov.z = v.z * r * wv.z; ov.w = v.w * r * wv.w;
        *reinterpret_cast<float4*>(out + (size_t)t * H_DIM + d) = ov;
    }
}

// ---------------------------------------------------------------- generic f32 GEMM
__global__ __launch_bounds__(256) void gemm_f32(const float* __restrict__ A,
                                                const float* __restrict__ B,
                                                float* __restrict__ C,
                                                float* __restrict__ C2,
                                                const float* __restrict__ R,
                                                int M, int N, int K) {
    __shared__ float As[64][17];
    __shared__ float Bs[16][64];
    int row0 = blockIdx.y * 64, col0 = blockIdx.x * 64;
    int tid = threadIdx.x, tx = tid & 15, ty = tid >> 4;
    float acc[4][4] = {};
    for (int k0 = 0; k0 < K; k0 += 16) {
        {
            int r = tid >> 2, kk = (tid & 3) * 4;
            float4 v = *reinterpret_cast<const float4*>(&A[(size_t)(row0 + r) * K + k0 + kk]);
            As[r][kk] = v.x; As[r][kk + 1] = v.y; As[r][kk + 2] = v.z; As[r][kk + 3] = v.w;
        }
        {
            int kk = tid >> 6, c = tid & 63;
            #pragma unroll
            for (int i = 0; i < 4; i++)
                Bs[kk + 4 * i][c] = B[(size_t)(k0 + kk + 4 * i) * N + col0 + c];
        }
        __syncthreads();
        #pragma unroll
        for (int kk = 0; kk < 16; kk++) {
            float a[4], b[4];
            #pragma unroll
            for (int i = 0; i < 4; i++) a[i] = As[ty * 4 + i][kk];
            #pragma unroll
            for (int j = 0; j < 4; j++) b[j] = Bs[kk][tx * 4 + j];
            #pragma unroll
            for (int i = 0; i < 4; i++)
                #pragma unroll
                for (int j = 0; j < 4; j++) acc[i][j] += a[i] * b[j];
        }
        __syncthreads();
    }
    for (int i = 0; i < 4; i++) {
        int r = row0 + ty * 4 + i;
        for (int j = 0; j < 4; j++) {
            int c = col0 + tx * 4 + j;
            float v = acc[i][j];
            if (R)  v += R[(size_t)r * N + c];
            C[(size_t)r * N + c] = v;
            if (C2) C2[(size_t)r * N + c] = v;
        }
    }
}

// ---------------------------------------------------------------- pack: RoPE + bf16 cast for Q,K
// grid (SEQ, NH+NKV), 128 threads. q heads scaled by HD^-0.5.
__global__ __launch_bounds__(128) void pack_qk(const float* __restrict__ qkv,
                                               const int* __restrict__ positions,
                                               unsigned short* __restrict__ Qb,
                                               unsigned short* __restrict__ Kb) {
    int t = blockIdx.x;
    int h = blockIdx.y;             // 0..15 q, 16..19 k  (offset = h*HD in both cases)
    int i = threadIdx.x;            // output dim 0..127
    int ii = i & 63;
    float pos = (float)positions[t];
    float inv = __powf(THETA, -(float)ii * (1.0f / 64.0f));
    float ang = pos * inv;
    float s, c;
    __sincosf(ang, &s, &c);
    size_t src = (size_t)t * QKV_N + (size_t)h * HD;
    float x1 = qkv[src + ii], x2 = qkv[src + 64 + ii];
    float val = (i < 64) ? (x1 * c - x2 * s) : (x2 * c + x1 * s);
    if (h < NH) {
        Qb[((size_t)h * SEQ + t) * HD + i] = f2bf(val * 0.08838834764831845f);
    } else {
        Kb[((size_t)(h - NH) * SEQ + t) * HD + i] = f2bf(val);
    }
}

// ---------------------------------------------------------------- pack: V transposed to [NKV][HD][S] bf16
// grid (SEQ/64, HD/64, NKV), 256 threads
__global__ __launch_bounds__(256) void pack_vt(const float* __restrict__ qkv,
                                               unsigned short* __restrict__ Vt) {
    int t0 = blockIdx.x * 64;
    int d0 = blockIdx.y * 64;
    int kvh = blockIdx.z;
    __shared__ unsigned short tile[64][65];
    int tid = threadIdx.x;
    int c = tid & 63;
    #pragma unroll
    for (int rep = 0; rep < 16; rep++) {
        int r = rep * 4 + (tid >> 6);
        tile[r][c] = f2bf(qkv[(size_t)(t0 + r) * QKV_N + (NH + NKV) * HD + kvh * HD + d0 + c]);
    }
    __syncthreads();
    #pragma unroll
    for (int rep = 0; rep < 16; rep++) {
        int r = rep * 4 + (tid >> 6);   // d within tile
        Vt[((size_t)kvh * HD + d0 + r) * SEQ + t0 + c] = tile[c][r];
    }
}

// ---------------------------------------------------------------- flash attention, 1 wave / 16 q-rows
// grid (SEQ/16, NH), 64 threads
__global__ __launch_bounds__(64) void attn_mfma(const unsigned short* __restrict__ Qb,
                                                const unsigned short* __restrict__ Kb,
                                                const unsigned short* __restrict__ Vt,
                                                float* __restrict__ o) {
    int qt = blockIdx.x;
    int h  = blockIdx.y;
    int kvh = h >> 2;
    int q0 = qt * 16;
    int l = threadIdx.x;
    int lo = l & 15, g = l >> 4;

    __shared__ alignas(16) unsigned short pbuf[16][40];   // [q][kv(32)+pad]

    // Q fragments: lane holds Q[q0+lo][ks*32 + g*8 + j]
    bf16x8 qf[4];
    const unsigned short* qp = Qb + ((size_t)h * SEQ + q0 + lo) * HD + g * 8;
    #pragma unroll
    for (int ks = 0; ks < 4; ks++)
        qf[ks] = *(const bf16x8*)(qp + ks * 32);

    f32x4 accO[8];
    #pragma unroll
    for (int nd = 0; nd < 8; nd++) accO[nd] = (f32x4){0.f, 0.f, 0.f, 0.f};
    float mrun[4], lrun[4];
    #pragma unroll
    for (int r = 0; r < 4; r++) { mrun[r] = -INFINITY; lrun[r] = 0.f; }

    int nc = (q0 + 16 + 31) / 32;
    for (int ch = 0; ch < nc; ch++) {
        int kv0 = ch * 32;
        // ---- S = Q K^T for 32 kv cols (two 16-wide tiles)
        f32x4 accS[2];
        accS[0] = (f32x4){0.f, 0.f, 0.f, 0.f};
        accS[1] = (f32x4){0.f, 0.f, 0.f, 0.f};
        const unsigned short* kp = Kb + ((size_t)kvh * SEQ + kv0 + lo) * HD + g * 8;
        #pragma unroll
        for (int n = 0; n < 2; n++) {
            const unsigned short* kpn = kp + (size_t)n * 16 * HD;
            #pragma unroll
            for (int ks = 0; ks < 4; ks++) {
                bf16x8 kf = *(const bf16x8*)(kpn + ks * 32);
                accS[n] = __builtin_amdgcn_mfma_f32_16x16x32_bf16(qf[ks], kf, accS[n], 0, 0, 0);
            }
        }
        // ---- causal mask (only final chunk can touch kv > q)
        if (ch == nc - 1) {
            #pragma unroll
            for (int n = 0; n < 2; n++)
                #pragma unroll
                for (int r = 0; r < 4; r++) {
                    int kv = kv0 + n * 16 + lo;
                    int q  = q0 + g * 4 + r;
                    if (kv > q) accS[n][r] = -1e30f;
                }
        }
        // ---- online softmax (rows g*4+r live across the 16-lane group)
        float mt[4], fac[4];
        #pragma unroll
        for (int r = 0; r < 4; r++) {
            float m = fmaxf(accS[0][r], accS[1][r]);
            #pragma unroll
            for (int off = 1; off < 16; off <<= 1) m = fmaxf(m, __shfl_xor(m, off));
            mt[r] = fmaxf(mrun[r], m);
            fac[r] = __expf(mrun[r] - mt[r]);
        }
        float psum[4] = {0.f, 0.f, 0.f, 0.f};
        #pragma unroll
        for (int n = 0; n < 2; n++)
            #pragma unroll
            for (int r = 0; r < 4; r++) {
                float p = __expf(accS[n][r] - mt[r]);
                psum[r] += p;
                pbuf[g * 4 + r][n * 16 + lo] = f2bf(p);
            }
        #pragma unroll
        for (int r = 0; r < 4; r++) {
            float s = psum[r];
            #pragma unroll
            for (int off = 1; off < 16; off <<= 1) s += __shfl_xor(s, off);
            lrun[r] = lrun[r] * fac[r] + s;
            mrun[r] = mt[r];
        }
        #pragma unroll
        for (int nd = 0; nd < 8; nd++)
            #pragma unroll
            for (int r = 0; r < 4; r++) accO[nd][r] *= fac[r];
        // ---- PV: A-frag = P[lo][g*8+j] from LDS, B-frag = Vt rows (contiguous)
        __builtin_amdgcn_sched_barrier(0);
        bf16x8 pf = *(const bf16x8*)(&pbuf[lo][g * 8]);
        const unsigned short* vp = Vt + ((size_t)kvh * HD + lo) * SEQ + kv0 + g * 8;
        #pragma unroll
        for (int nd = 0; nd < 8; nd++) {
            bf16x8 vf = *(const bf16x8*)(vp + (size_t)nd * 16 * SEQ);
            accO[nd] = __builtin_amdgcn_mfma_f32_16x16x32_bf16(pf, vf, accO[nd], 0, 0, 0);
        }
        __builtin_amdgcn_sched_barrier(0);
    }
    float inv[4];
    #pragma unroll
    for (int r = 0; r < 4; r++) inv[r] = 1.0f / lrun[r];
    #pragma unroll
    for (int nd = 0; nd < 8; nd++)
        #pragma unroll
        for (int r = 0; r < 4; r++)
            o[(size_t)(q0 + g * 4 + r) * H_DIM + h * HD + nd * 16 + lo] = accO[nd][r] * inv[r];
}

// ---------------------------------------------------------------- router
__global__ __launch_bounds__(256) void router_kernel(const float* __restrict__ x,
                                                     const float* __restrict__ gate_w,
                                                     const float* __restrict__ gate_bias,
                                                     int* __restrict__ toklist,
                                                     float* __restrict__ tokw,
                                                     int* __restrict__ cnt) {
    int t = blockIdx.x;
    const float* xt = x + (size_t)t * H_DIM;
    __shared__ float logits[NE];
    __shared__ float red[4];
    for (int e = 0; e < NE; e++) {
        float p = 0.f;
        for (int d = threadIdx.x; d < H_DIM; d += 256) p += xt[d] * gate_w[(size_t)e * H_DIM + d];
        for (int off = 1; off < 64; off <<= 1) p += __shfl_xor(p, off);
        if ((threadIdx.x & 63) == 0) red[threadIdx.x >> 6] = p;
        __syncthreads();
        if (threadIdx.x == 0) logits[e] = red[0] + red[1] + red[2] + red[3];
        __syncthreads();
    }
    if (threadIdx.x == 0) {
        float sig[NE], sb[NE];
        for (int e = 0; e < NE; e++) {
            sig[e] = 1.f / (1.f + expf(-logits[e]));
            sb[e] = sig[e] + gate_bias[e];
        }
        float gs[NG];
        for (int g = 0; g < NG; g++) {
            float m1 = -1e30f, m2 = -1e30f;
            for (int i = 0; i < 4; i++) {
                float v = sb[g * 4 + i];
                if (v > m1) { m2 = m1; m1 = v; } else if (v > m2) m2 = v;
            }
            gs[g] = m1 + m2;
        }
        int g1 = 0;
        for (int g = 1; g < NG; g++) if (gs[g] > gs[g1]) g1 = g;
        int g2 = -1;
        for (int g = 0; g < NG; g++) {
            if (g == g1) continue;
            if (g2 < 0 || gs[g] > gs[g2]) g2 = g;
        }
        bool allowed[NE], used[NE];
        for (int e = 0; e < NE; e++) { int g = e >> 2; allowed[e] = (g == g1 || g == g2); used[e] = false; }
        int sel[TOPK]; float wsel[TOPK]; float wsum = 0.f;
        for (int k = 0; k < TOPK; k++) {
            int best = -1; float bv = -1e30f;
            for (int e = 0; e < NE; e++) {
                if (!allowed[e] || used[e]) continue;
                if (best < 0 || sb[e] > bv) { best = e; bv = sb[e]; }
            }
            used[best] = true; sel[k] = best; wsel[k] = sig[best]; wsum += sig[best];
        }
        float invs = 1.f / (wsum + 1e-20f);
        for (int k = 0; k < TOPK; k++) {
            int e = sel[k];
            int slot = atomicAdd(&cnt[e], 1);
            toklist[e * SEQ + slot] = t;
            tokw[e * SEQ + slot] = wsel[k] * invs;
        }
    }
}

__global__ void prefix_kernel(const int* __restrict__ cnt, int* __restrict__ base) {
    if (threadIdx.x == 0) {
        int s = 0;
        for (int e = 0; e < NE; e++) { base[e] = s; s += cnt[e]; }
    }
}

// ---------------------------------------------------------------- MoE GEMM1
__global__ __launch_bounds__(256) void moe_gemm1(const float* __restrict__ x,
                                                 const float* __restrict__ gup,
                                                 const int* __restrict__ toklist,
                                                 const int* __restrict__ cnt,
                                                 const int* __restrict__ base,
                                                 float* __restrict__ act) {
    int e = blockIdx.z;
    int ce = cnt[e];
    int t0 = blockIdx.y * 64;
    if (t0 >= ce) return;
    int f0 = blockIdx.x * 64;
    __shared__ float Xs[64][17];
    __shared__ float Gs[16][64];
    __shared__ float Us[16][64];
    __shared__ int toks[64];
    int tid = threadIdx.x, tx = tid & 15, ty = tid >> 4;
    if (tid < 64) toks[tid] = (t0 + tid < ce) ? toklist[e * SEQ + t0 + tid] : toklist[e * SEQ + t0];
    __syncthreads();
    float accG[4][4] = {}, accU[4][4] = {};
    const float* W = gup + (size_t)e * H_DIM * (2 * DFF);
    for (int k0 = 0; k0 < H_DIM; k0 += 16) {
        {
            int r = tid >> 2, kk = (tid & 3) * 4;
            float4 v = *reinterpret_cast<const float4*>(&x[(size_t)toks[r] * H_DIM + k0 + kk]);
            Xs[r][kk] = v.x; Xs[r][kk + 1] = v.y; Xs[r][kk + 2] = v.z; Xs[r][kk + 3] = v.w;
        }
        {
            int kk = tid >> 6, c = tid & 63;
            #pragma unroll
            for (int i = 0; i < 4; i++) {
                const float* wr = W + (size_t)(k0 + kk + 4 * i) * (2 * DFF);
                Gs[kk + 4 * i][c] = wr[f0 + c];
                Us[kk + 4 * i][c] = wr[DFF + f0 + c];
            }
        }
        __syncthreads();
        #pragma unroll
        for (int kk = 0; kk < 16; kk++) {
            float a[4], bg[4], bu[4];
            #pragma unroll
            for (int i = 0; i < 4; i++) a[i] = Xs[ty * 4 + i][kk];
            #pragma unroll
            for (int j = 0; j < 4; j++) { bg[j] = Gs[kk][tx * 4 + j]; bu[j] = Us[kk][tx * 4 + j]; }
            #pragma unroll
            for (int i = 0; i < 4; i++)
                #pragma unroll
                for (int j = 0; j < 4; j++) { accG[i][j] += a[i] * bg[j]; accU[i][j] += a[i] * bu[j]; }
        }
        __syncthreads();
    }
    int b = base[e];
    for (int i = 0; i < 4; i++) {
        int slot = t0 + ty * 4 + i;
        if (slot >= ce) break;
        float* arow = act + (size_t)(b + slot) * DFF + f0;
        for (int j = 0; j < 4; j++) {
            float g = accG[i][j], u = accU[i][j];
            arow[tx * 4 + j] = (g / (1.f + expf(-g))) * u;
        }
    }
}

// ---------------------------------------------------------------- MoE GEMM2
__global__ __launch_bounds__(256) void moe_gemm2(const float* __restrict__ act,
                                                 const float* __restrict__ down,
                                                 const int* __restrict__ toklist,
                                                 const float* __restrict__ tokw,
                                                 const int* __restrict__ cnt,
                                                 const int* __restrict__ base,
                                                 float* __restrict__ out) {
    int e = blockIdx.z;
    int ce = cnt[e];
    int t0 = blockIdx.y * 64;
    if (t0 >= ce) return;
    int c0 = blockIdx.x * 64;
    __shared__ float As[64][17];
    __shared__ float Bs[16][64];
    int tid = threadIdx.x, tx = tid & 15, ty = tid >> 4;
    int b = base[e];
    float acc[4][4] = {};
    const float* W = down + (size_t)e * DFF * H_DIM;
    for (int k0 = 0; k0 < DFF; k0 += 16) {
        {
            int r = tid >> 2, kk = (tid & 3) * 4;
            int slot = (t0 + r < ce) ? (t0 + r) : t0;
            float4 v = *reinterpret_cast<const float4*>(&act[(size_t)(b + slot) * DFF + k0 + kk]);
            As[r][kk] = v.x; As[r][kk + 1] = v.y; As[r][kk + 2] = v.z; As[r][kk + 3] = v.w;
        }
        {
            int kk = tid >> 6, c = tid & 63;
            #pragma unroll
            for (int i = 0; i < 4; i++)
                Bs[kk + 4 * i][c] = W[(size_t)(k0 + kk + 4 * i) * H_DIM + c0 + c];
        }
        __syncthreads();
        #pragma unroll
        for (int kk = 0; kk < 16; kk++) {
            float a[4], bb[4];
            #pragma unroll
            for (int i = 0; i < 4; i++) a[i] = As[ty * 4 + i][kk];
            #pragma unroll
            for (int j = 0; j < 4; j++) bb[j] = Bs[kk][tx * 4 + j];
            #pragma unroll
            for (int i = 0; i < 4; i++)
                #pragma unroll
                for (int j = 0; j < 4; j++) acc[i][j] += a[i] * bb[j];
        }
        __syncthreads();
    }
    for (int i = 0; i < 4; i++) {
        int slot = t0 + ty * 4 + i;
        if (slot >= ce) break;
        int tok = toklist[e * SEQ + slot];
        float w = tokw[e * SEQ + slot];
        for (int j = 0; j < 4; j++)
            atomicAdd(&out[(size_t)tok * H_DIM + c0 + tx * 4 + j], w * acc[i][j]);
    }
}

// ---------------------------------------------------------------- launch
extern "C" void kernel_launch(void* const* d_in, const int* in_sizes, int n_in,
                              void* d_out, int out_size, void* d_ws, size_t ws_size,
                              hipStream_t stream) {
    const float* hidden     = (const float*)d_in[0];
    const int*   positions  = (const int*)d_in[1];
    const float* in_norm_w  = (const float*)d_in[2];
    const float* post_norm_w= (const float*)d_in[3];
    const float* qkv_w      = (const float*)d_in[4];
    const float* o_w        = (const float*)d_in[5];
    const float* gate_w     = (const float*)d_in[6];
    const float* gate_bias  = (const float*)d_in[7];
    const float* gate_up_w  = (const float*)d_in[8];
    const float* down_w     = (const float*)d_in[9];
    float* out = (float*)d_out;

    float* ws   = (float*)d_ws;
    float* h    = ws;                         // 1024*2048
    float* qkv  = h    + (size_t)SEQ * H_DIM; // 1024*3072
    float* o    = qkv  + (size_t)SEQ * QKV_N; // 1024*2048
    float* h2   = o    + (size_t)SEQ * H_DIM; // 1024*2048
    float* x    = h2   + (size_t)SEQ * H_DIM; // 1024*2048
    float* act  = x    + (size_t)SEQ * H_DIM; // 4096*1024
    float* tokw = act  + (size_t)4 * SEQ * DFF;   // 16*1024
    int* toklist = (int*)(tokw + NE * SEQ);   // 16*1024
    int* cnt  = toklist + NE * SEQ;           // 16
    int* base = cnt + NE;                     // 16
    unsigned short* Qb = (unsigned short*)(base + NE);       // 16*1024*128 bf16
    unsigned short* Kb = Qb + (size_t)NH * SEQ * HD;         // 4*1024*128
    unsigned short* Vt = Kb + (size_t)NKV * SEQ * HD;        // 4*128*1024

    // 1. pre-attention RMSNorm
    rmsnorm_kernel<<<SEQ, 256, 0, stream>>>(hidden, in_norm_w, h);
    // 2. qkv projection (f32)
    gemm_f32<<<dim3(QKV_N / 64, SEQ / 64), 256, 0, stream>>>(h, qkv_w, qkv, nullptr, nullptr,
                                                             SEQ, QKV_N, H_DIM);
    // 3. pack: RoPE+bf16 Q/K, transpose+bf16 V
    pack_qk<<<dim3(SEQ, NH + NKV), 128, 0, stream>>>(qkv, positions, Qb, Kb);
    pack_vt<<<dim3(SEQ / 64, HD / 64, NKV), 256, 0, stream>>>(qkv, Vt);
    // 4. flash attention (bf16 MFMA)
    attn_mfma<<<dim3(SEQ / 16, NH), 64, 0, stream>>>(Qb, Kb, Vt, o);
    // 5. o projection + residual -> h2 (ws) and d_out
    gemm_f32<<<dim3(H_DIM / 64, SEQ / 64), 256, 0, stream>>>(o, o_w, h2, out, hidden,
                                                             SEQ, H_DIM, H_DIM);
    // 6. post-attention RMSNorm
    rmsnorm_kernel<<<SEQ, 256, 0, stream>>>(h2, post_norm_w, x);
    // 7. router
    hipMemsetAsync(cnt, 0, NE * sizeof(int), stream);
    router_kernel<<<SEQ, 256, 0, stream>>>(x, gate_w, gate_bias, toklist, tokw, cnt);
    prefix_kernel<<<1, 64, 0, stream>>>(cnt, base);
    // 8. MoE
    moe_gemm1<<<dim3(DFF / 64, SEQ / 64, NE), 256, 0, stream>>>(x, gate_up_w, toklist, cnt, base, act);
    moe_gemm2<<<dim3(H_DIM / 64, SEQ / 64, NE), 256, 0, stream>>>(act, down_w, toklist, tokw, cnt, base, out);
}

// Round 3
// 578.017 us; speedup vs baseline: 4.2905x; 2.4572x over previous
//
#include <hip/hip_runtime.h>
#include <hip/hip_bf16.h>
#include <math.h>

#define H_DIM   2048
#define NH      16
#define NKV     4
#define HD      128
#define NE      16
#define TOPK    4
#define DFF     1024
#define NG      4
#define TG      2
#define SEQ     1024
#define QKV_N   3072          // (NH + 2*NKV)*HD
#define EPS_RMS 1e-6f
#define THETA   1000000.0f

typedef __attribute__((ext_vector_type(8))) short bf16x8;
typedef __attribute__((ext_vector_type(4))) short s16x4;
typedef __attribute__((ext_vector_type(4))) float f32x4;

__device__ inline unsigned short f2bf(float x) {
    unsigned u = __builtin_bit_cast(unsigned, x);
    unsigned r = (u + 0x7FFFu + ((u >> 16) & 1u)) >> 16;
    return (unsigned short)r;
}

// ---------------------------------------------------------------- RMSNorm (f32 in, optional f32 + bf16 out)
__global__ __launch_bounds__(256) void rmsnorm_dual(const float* __restrict__ in,
                                                    const float* __restrict__ w,
                                                    float* __restrict__ outf,
                                                    unsigned short* __restrict__ outb) {
    int t = blockIdx.x;
    const float* xt = in + (size_t)t * H_DIM;
    float ss = 0.f;
    for (int d = threadIdx.x * 4; d < H_DIM; d += 1024) {
        float4 v = *reinterpret_cast<const float4*>(xt + d);
        ss += v.x * v.x + v.y * v.y + v.z * v.z + v.w * v.w;
    }
    for (int off = 1; off < 64; off <<= 1) ss += __shfl_xor(ss, off);
    __shared__ float red[4];
    __shared__ float srms;
    if ((threadIdx.x & 63) == 0) red[threadIdx.x >> 6] = ss;
    __syncthreads();
    if (threadIdx.x == 0)
        srms = rsqrtf((red[0] + red[1] + red[2] + red[3]) * (1.f / H_DIM) + EPS_RMS);
    __syncthreads();
    float r = srms;
    for (int d = threadIdx.x * 4; d < H_DIM; d += 1024) {
        float4 v  = *reinterpret_cast<const float4*>(xt + d);
        float4 wv = *reinterpret_cast<const float4*>(w + d);
        float4 ov;
        ov.x = v.x * r * wv.x; ov.y = v.y * r * wv.y;
        ov.z = v.z * r * wv.z; ov.w = v.w * r * wv.w;
        if (outf) *reinterpret_cast<float4*>(outf + (size_t)t * H_DIM + d) = ov;
        if (outb) {
            s16x4 bv = (s16x4){(short)f2bf(ov.x), (short)f2bf(ov.y),
                               (short)f2bf(ov.z), (short)f2bf(ov.w)};
            *reinterpret_cast<s16x4*>(outb + (size_t)t * H_DIM + d) = bv;
        }
    }
}

// ---------------------------------------------------------------- generic bf16-MFMA GEMM
// C[M,N](f32) = A(bf16)[M,K] @ B(f32)[K,N] (+R), optional dup to C2.
// BM=128, BN=128, BK=32, 256 threads (4 waves, each 64x64).
__global__ __launch_bounds__(256) void gemm_bf16(const unsigned short* __restrict__ A,
                                                 const float* __restrict__ B,
                                                 float* __restrict__ C,
                                                 float* __restrict__ C2,
                                                 const float* __restrict__ R,
                                                 int M, int N, int K) {
    __shared__ unsigned short As[128 * 40];
    __shared__ unsigned short Bs[128 * 40];
    int row0 = blockIdx.y * 128, col0 = blockIdx.x * 128;
    int t = threadIdx.x;
    int w = t >> 6, lane = t & 63, lo = lane & 15, g = lane >> 4;
    int wr = (w >> 1) * 64, wc = (w & 1) * 64;
    f32x4 acc[4][4];
    #pragma unroll
    for (int mi = 0; mi < 4; mi++)
        #pragma unroll
        for (int ni = 0; ni < 4; ni++) acc[mi][ni] = (f32x4){0.f, 0.f, 0.f, 0.f};
    int ar = t >> 1, ak = (t & 1) * 16;
    int bn = t & 127, bk = (t >> 7) * 8;
    for (int k0 = 0; k0 < K; k0 += 32) {
        const unsigned short* ga = A + (size_t)(row0 + ar) * K + k0 + ak;
        bf16x8 a0 = *(const bf16x8*)ga;
        bf16x8 a1 = *(const bf16x8*)(ga + 8);
        *(bf16x8*)&As[ar * 40 + ak] = a0;
        *(bf16x8*)&As[ar * 40 + ak + 8] = a1;
        #pragma unroll
        for (int p = 0; p < 2; p++) {
            int kb = bk + p * 16;
            unsigned short hh[8];
            #pragma unroll
            for (int j = 0; j < 8; j++)
                hh[j] = f2bf(B[(size_t)(k0 + kb + j) * N + col0 + bn]);
            *(s16x4*)&Bs[bn * 40 + kb]     = (s16x4){(short)hh[0], (short)hh[1], (short)hh[2], (short)hh[3]};
            *(s16x4*)&Bs[bn * 40 + kb + 4] = (s16x4){(short)hh[4], (short)hh[5], (short)hh[6], (short)hh[7]};
        }
        __syncthreads();
        bf16x8 af[4], bfr[4];
        #pragma unroll
        for (int mi = 0; mi < 4; mi++)
            af[mi] = *(const bf16x8*)&As[(wr + mi * 16 + lo) * 40 + g * 8];
        #pragma unroll
        for (int ni = 0; ni < 4; ni++)
            bfr[ni] = *(const bf16x8*)&Bs[(wc + ni * 16 + lo) * 40 + g * 8];
        #pragma unroll
        for (int mi = 0; mi < 4; mi++)
            #pragma unroll
            for (int ni = 0; ni < 4; ni++)
                acc[mi][ni] = __builtin_amdgcn_mfma_f32_16x16x32_bf16(af[mi], bfr[ni], acc[mi][ni], 0, 0, 0);
        __syncthreads();
    }
    #pragma unroll
    for (int mi = 0; mi < 4; mi++)
        #pragma unroll
        for (int ni = 0; ni < 4; ni++)
            #pragma unroll
            for (int r = 0; r < 4; r++) {
                int row = row0 + wr + mi * 16 + g * 4 + r;
                int col = col0 + wc + ni * 16 + lo;
                size_t idx = (size_t)row * N + col;
                float v = acc[mi][ni][r];
                if (R)  v += R[idx];
                C[idx] = v;
                if (C2) C2[idx] = v;
            }
}

// ---------------------------------------------------------------- pack: RoPE + bf16 cast for Q,K
__global__ __launch_bounds__(128) void pack_qk(const float* __restrict__ qkv,
                                               const int* __restrict__ positions,
                                               unsigned short* __restrict__ Qb,
                                               unsigned short* __restrict__ Kb) {
    int t = blockIdx.x;
    int h = blockIdx.y;
    int i = threadIdx.x;
    int ii = i & 63;
    float pos = (float)positions[t];
    float inv = __powf(THETA, -(float)ii * (1.0f / 64.0f));
    float ang = pos * inv;
    float s, c;
    __sincosf(ang, &s, &c);
    size_t src = (size_t)t * QKV_N + (size_t)h * HD;
    float x1 = qkv[src + ii], x2 = qkv[src + 64 + ii];
    float val = (i < 64) ? (x1 * c - x2 * s) : (x2 * c + x1 * s);
    if (h < NH) {
        Qb[((size_t)h * SEQ + t) * HD + i] = f2bf(val * 0.08838834764831845f);
    } else {
        Kb[((size_t)(h - NH) * SEQ + t) * HD + i] = f2bf(val);
    }
}

// ---------------------------------------------------------------- pack: V transposed to [NKV][HD][S] bf16
__global__ __launch_bounds__(256) void pack_vt(const float* __restrict__ qkv,
                                               unsigned short* __restrict__ Vt) {
    int t0 = blockIdx.x * 64;
    int d0 = blockIdx.y * 64;
    int kvh = blockIdx.z;
    __shared__ unsigned short tile[64][65];
    int tid = threadIdx.x;
    int c = tid & 63;
    #pragma unroll
    for (int rep = 0; rep < 16; rep++) {
        int r = rep * 4 + (tid >> 6);
        tile[r][c] = f2bf(qkv[(size_t)(t0 + r) * QKV_N + (NH + NKV) * HD + kvh * HD + d0 + c]);
    }
    __syncthreads();
    #pragma unroll
    for (int rep = 0; rep < 16; rep++) {
        int r = rep * 4 + (tid >> 6);
        Vt[((size_t)kvh * HD + d0 + r) * SEQ + t0 + c] = tile[c][r];
    }
}

// ---------------------------------------------------------------- flash attention, 1 wave / 16 q-rows, bf16 out
__global__ __launch_bounds__(64) void attn_mfma(const unsigned short* __restrict__ Qb,
                                                const unsigned short* __restrict__ Kb,
                                                const unsigned short* __restrict__ Vt,
                                                unsigned short* __restrict__ ob) {
    int qt = blockIdx.x;
    int h  = blockIdx.y;
    int kvh = h >> 2;
    int q0 = qt * 16;
    int l = threadIdx.x;
    int lo = l & 15, g = l >> 4;

    __shared__ alignas(16) unsigned short pbuf[16][40];

    bf16x8 qf[4];
    const unsigned short* qp = Qb + ((size_t)h * SEQ + q0 + lo) * HD + g * 8;
    #pragma unroll
    for (int ks = 0; ks < 4; ks++)
        qf[ks] = *(const bf16x8*)(qp + ks * 32);

    f32x4 accO[8];
    #pragma unroll
    for (int nd = 0; nd < 8; nd++) accO[nd] = (f32x4){0.f, 0.f, 0.f, 0.f};
    float mrun[4], lrun[4];
    #pragma unroll
    for (int r = 0; r < 4; r++) { mrun[r] = -INFINITY; lrun[r] = 0.f; }

    int nc = (q0 + 16 + 31) / 32;
    for (int ch = 0; ch < nc; ch++) {
        int kv0 = ch * 32;
        f32x4 accS[2];
        accS[0] = (f32x4){0.f, 0.f, 0.f, 0.f};
        accS[1] = (f32x4){0.f, 0.f, 0.f, 0.f};
        const unsigned short* kp = Kb + ((size_t)kvh * SEQ + kv0 + lo) * HD + g * 8;
        #pragma unroll
        for (int n = 0; n < 2; n++) {
            const unsigned short* kpn = kp + (size_t)n * 16 * HD;
            #pragma unroll
            for (int ks = 0; ks < 4; ks++) {
                bf16x8 kf = *(const bf16x8*)(kpn + ks * 32);
                accS[n] = __builtin_amdgcn_mfma_f32_16x16x32_bf16(qf[ks], kf, accS[n], 0, 0, 0);
            }
        }
        if (ch == nc - 1) {
            #pragma unroll
            for (int n = 0; n < 2; n++)
                #pragma unroll
                for (int r = 0; r < 4; r++) {
                    int kv = kv0 + n * 16 + lo;
                    int q  = q0 + g * 4 + r;
                    if (kv > q) accS[n][r] = -1e30f;
                }
        }
        float mt[4], fac[4];
        #pragma unroll
        for (int r = 0; r < 4; r++) {
            float m = fmaxf(accS[0][r], accS[1][r]);
            #pragma unroll
            for (int off = 1; off < 16; off <<= 1) m = fmaxf(m, __shfl_xor(m, off));
            mt[r] = fmaxf(mrun[r], m);
            fac[r] = __expf(mrun[r] - mt[r]);
        }
        float psum[4] = {0.f, 0.f, 0.f, 0.f};
        #pragma unroll
        for (int n = 0; n < 2; n++)
            #pragma unroll
            for (int r = 0; r < 4; r++) {
                float p = __expf(accS[n][r] - mt[r]);
                psum[r] += p;
                pbuf[g * 4 + r][n * 16 + lo] = f2bf(p);
            }
        #pragma unroll
        for (int r = 0; r < 4; r++) {
            float s = psum[r];
            #pragma unroll
            for (int off = 1; off < 16; off <<= 1) s += __shfl_xor(s, off);
            lrun[r] = lrun[r] * fac[r] + s;
            mrun[r] = mt[r];
        }
        #pragma unroll
        for (int nd = 0; nd < 8; nd++)
            #pragma unroll
            for (int r = 0; r < 4; r++) accO[nd][r] *= fac[r];
        __builtin_amdgcn_sched_barrier(0);
        bf16x8 pf = *(const bf16x8*)(&pbuf[lo][g * 8]);
        const unsigned short* vp = Vt + ((size_t)kvh * HD + lo) * SEQ + kv0 + g * 8;
        #pragma unroll
        for (int nd = 0; nd < 8; nd++) {
            bf16x8 vf = *(const bf16x8*)(vp + (size_t)nd * 16 * SEQ);
            accO[nd] = __builtin_amdgcn_mfma_f32_16x16x32_bf16(pf, vf, accO[nd], 0, 0, 0);
        }
        __builtin_amdgcn_sched_barrier(0);
    }
    float inv[4];
    #pragma unroll
    for (int r = 0; r < 4; r++) inv[r] = 1.0f / lrun[r];
    #pragma unroll
    for (int nd = 0; nd < 8; nd++)
        #pragma unroll
        for (int r = 0; r < 4; r++)
            ob[(size_t)(q0 + g * 4 + r) * H_DIM + h * HD + nd * 16 + lo] = f2bf(accO[nd][r] * inv[r]);
}

// ---------------------------------------------------------------- router
__global__ __launch_bounds__(256) void router_kernel(const float* __restrict__ x,
                                                     const float* __restrict__ gate_w,
                                                     const float* __restrict__ gate_bias,
                                                     int* __restrict__ toklist,
                                                     float* __restrict__ tokw,
                                                     int* __restrict__ cnt) {
    int t = blockIdx.x;
    const float* xt = x + (size_t)t * H_DIM;
    __shared__ float logits[NE];
    __shared__ float red[4];
    for (int e = 0; e < NE; e++) {
        float p = 0.f;
        for (int d = threadIdx.x; d < H_DIM; d += 256) p += xt[d] * gate_w[(size_t)e * H_DIM + d];
        for (int off = 1; off < 64; off <<= 1) p += __shfl_xor(p, off);
        if ((threadIdx.x & 63) == 0) red[threadIdx.x >> 6] = p;
        __syncthreads();
        if (threadIdx.x == 0) logits[e] = red[0] + red[1] + red[2] + red[3];
        __syncthreads();
    }
    if (threadIdx.x == 0) {
        float sig[NE], sb[NE];
        for (int e = 0; e < NE; e++) {
            sig[e] = 1.f / (1.f + expf(-logits[e]));
            sb[e] = sig[e] + gate_bias[e];
        }
        float gs[NG];
        for (int g = 0; g < NG; g++) {
            float m1 = -1e30f, m2 = -1e30f;
            for (int i = 0; i < 4; i++) {
                float v = sb[g * 4 + i];
                if (v > m1) { m2 = m1; m1 = v; } else if (v > m2) m2 = v;
            }
            gs[g] = m1 + m2;
        }
        int g1 = 0;
        for (int g = 1; g < NG; g++) if (gs[g] > gs[g1]) g1 = g;
        int g2 = -1;
        for (int g = 0; g < NG; g++) {
            if (g == g1) continue;
            if (g2 < 0 || gs[g] > gs[g2]) g2 = g;
        }
        bool allowed[NE], used[NE];
        for (int e = 0; e < NE; e++) { int g = e >> 2; allowed[e] = (g == g1 || g == g2); used[e] = false; }
        int sel[TOPK]; float wsel[TOPK]; float wsum = 0.f;
        for (int k = 0; k < TOPK; k++) {
            int best = -1; float bv = -1e30f;
            for (int e = 0; e < NE; e++) {
                if (!allowed[e] || used[e]) continue;
                if (best < 0 || sb[e] > bv) { best = e; bv = sb[e]; }
            }
            used[best] = true; sel[k] = best; wsel[k] = sig[best]; wsum += sig[best];
        }
        float invs = 1.f / (wsum + 1e-20f);
        for (int k = 0; k < TOPK; k++) {
            int e = sel[k];
            int slot = atomicAdd(&cnt[e], 1);
            toklist[e * SEQ + slot] = t;
            tokw[e * SEQ + slot] = wsel[k] * invs;
        }
    }
}

__global__ void prefix_kernel(const int* __restrict__ cnt, int* __restrict__ base) {
    if (threadIdx.x == 0) {
        int s = 0;
        for (int e = 0; e < NE; e++) { base[e] = s; s += cnt[e]; }
    }
}

// ---------------------------------------------------------------- MoE GEMM1 (MFMA): act = silu(x@G)*(x@U), bf16 out
// BM=128, BN=64(G)+64(U), BK=32. grid (DFF/64, SEQ/128, NE)
__global__ __launch_bounds__(256) void moe_gemm1_mfma(const unsigned short* __restrict__ xb,
                                                      const float* __restrict__ gup,
                                                      const int* __restrict__ toklist,
                                                      const int* __restrict__ cnt,
                                                      const int* __restrict__ base,
                                                      unsigned short* __restrict__ act) {
    int e = blockIdx.z;
    int ce = cnt[e];
    int t0 = blockIdx.y * 128;
    if (t0 >= ce) return;
    int f0 = blockIdx.x * 64;
    __shared__ unsigned short As[128 * 40];
    __shared__ unsigned short BsG[64 * 40];
    __shared__ unsigned short BsU[64 * 40];
    __shared__ int toks[128];
    int t = threadIdx.x;
    if (t < 128) { int s = t0 + t; toks[t] = toklist[e * SEQ + (s < ce ? s : 0)]; }
    __syncthreads();
    int w = t >> 6, lane = t & 63, lo = lane & 15, g = lane >> 4;
    int wrb = (w >> 1) * 64, wcb = (w & 1) * 32;
    f32x4 accG[4][2], accU[4][2];
    #pragma unroll
    for (int mi = 0; mi < 4; mi++)
        #pragma unroll
        for (int ni = 0; ni < 2; ni++) {
            accG[mi][ni] = (f32x4){0.f, 0.f, 0.f, 0.f};
            accU[mi][ni] = (f32x4){0.f, 0.f, 0.f, 0.f};
        }
    int ar = t >> 1, ak = (t & 1) * 16;
    int bn = t & 63, bk = (t >> 6) * 8;
    const float* W = gup + (size_t)e * H_DIM * (2 * DFF);
    for (int k0 = 0; k0 < H_DIM; k0 += 32) {
        const unsigned short* ga = xb + (size_t)toks[ar] * H_DIM + k0 + ak;
        bf16x8 a0 = *(const bf16x8*)ga;
        bf16x8 a1 = *(const bf16x8*)(ga + 8);
        *(bf16x8*)&As[ar * 40 + ak] = a0;
        *(bf16x8*)&As[ar * 40 + ak + 8] = a1;
        unsigned short hg[8], hu[8];
        #pragma unroll
        for (int j = 0; j < 8; j++) {
            const float* wr = W + (size_t)(k0 + bk + j) * (2 * DFF);
            hg[j] = f2bf(wr[f0 + bn]);
            hu[j] = f2bf(wr[DFF + f0 + bn]);
        }
        *(s16x4*)&BsG[bn * 40 + bk]     = (s16x4){(short)hg[0], (short)hg[1], (short)hg[2], (short)hg[3]};
        *(s16x4*)&BsG[bn * 40 + bk + 4] = (s16x4){(short)hg[4], (short)hg[5], (short)hg[6], (short)hg[7]};
        *(s16x4*)&BsU[bn * 40 + bk]     = (s16x4){(short)hu[0], (short)hu[1], (short)hu[2], (short)hu[3]};
        *(s16x4*)&BsU[bn * 40 + bk + 4] = (s16x4){(short)hu[4], (short)hu[5], (short)hu[6], (short)hu[7]};
        __syncthreads();
        bf16x8 af[4], bg[2], bu[2];
        #pragma unroll
        for (int mi = 0; mi < 4; mi++)
            af[mi] = *(const bf16x8*)&As[(wrb + mi * 16 + lo) * 40 + g * 8];
        #pragma unroll
        for (int ni = 0; ni < 2; ni++) {
            bg[ni] = *(const bf16x8*)&BsG[(wcb + ni * 16 + lo) * 40 + g * 8];
            bu[ni] = *(const bf16x8*)&BsU[(wcb + ni * 16 + lo) * 40 + g * 8];
        }
        #pragma unroll
        for (int mi = 0; mi < 4; mi++)
            #pragma unroll
            for (int ni = 0; ni < 2; ni++) {
                accG[mi][ni] = __builtin_amdgcn_mfma_f32_16x16x32_bf16(af[mi], bg[ni], accG[mi][ni], 0, 0, 0);
                accU[mi][ni] = __builtin_amdgcn_mfma_f32_16x16x32_bf16(af[mi], bu[ni], accU[mi][ni], 0, 0, 0);
            }
        __syncthreads();
    }
    int b = base[e];
    #pragma unroll
    for (int mi = 0; mi < 4; mi++)
        #pragma unroll
        for (int ni = 0; ni < 2; ni++)
            #pragma unroll
            for (int r = 0; r < 4; r++) {
                int slot = t0 + wrb + mi * 16 + g * 4 + r;
                if (slot < ce) {
                    float gv = accG[mi][ni][r], uv = accU[mi][ni][r];
                    float a = (gv / (1.f + __expf(-gv))) * uv;
                    act[(size_t)(b + slot) * DFF + f0 + wcb + ni * 16 + lo] = f2bf(a);
                }
            }
}

// ---------------------------------------------------------------- MoE GEMM2 (MFMA): out += w * (act @ down)
// BM=128, BN=64, BK=32. grid (H_DIM/64, SEQ/128, NE)
__global__ __launch_bounds__(256) void moe_gemm2_mfma(const unsigned short* __restrict__ act,
                                                      const float* __restrict__ down,
                                                      const int* __restrict__ toklist,
                                                      const float* __restrict__ tokw,
                                                      const int* __restrict__ cnt,
                                                      const int* __restrict__ base,
                                                      float* __restrict__ out) {
    int e = blockIdx.z;
    int ce = cnt[e];
    int t0 = blockIdx.y * 128;
    if (t0 >= ce) return;
    int c0 = blockIdx.x * 64;
    __shared__ unsigned short As[128 * 40];
    __shared__ unsigned short Bs[64 * 40];
    int t = threadIdx.x;
    int w = t >> 6, lane = t & 63, lo = lane & 15, g = lane >> 4;
    int wrb = (w >> 1) * 64, wcb = (w & 1) * 32;
    int b = base[e];
    f32x4 acc[4][2];
    #pragma unroll
    for (int mi = 0; mi < 4; mi++)
        #pragma unroll
        for (int ni = 0; ni < 2; ni++) acc[mi][ni] = (f32x4){0.f, 0.f, 0.f, 0.f};
    int ar = t >> 1, ak = (t & 1) * 16;
    int bn = t & 63, bk = (t >> 6) * 8;
    const float* W = down + (size_t)e * DFF * H_DIM;
    for (int k0 = 0; k0 < DFF; k0 += 32) {
        int slot = t0 + ar;
        int arow = b + (slot < ce ? slot : t0);
        const unsigned short* ga = act + (size_t)arow * DFF + k0 + ak;
        bf16x8 a0 = *(const bf16x8*)ga;
        bf16x8 a1 = *(const bf16x8*)(ga + 8);
        *(bf16x8*)&As[ar * 40 + ak] = a0;
        *(bf16x8*)&As[ar * 40 + ak + 8] = a1;
        unsigned short hh[8];
        #pragma unroll
        for (int j = 0; j < 8; j++)
            hh[j] = f2bf(W[(size_t)(k0 + bk + j) * H_DIM + c0 + bn]);
        *(s16x4*)&Bs[bn * 40 + bk]     = (s16x4){(short)hh[0], (short)hh[1], (short)hh[2], (short)hh[3]};
        *(s16x4*)&Bs[bn * 40 + bk + 4] = (s16x4){(short)hh[4], (short)hh[5], (short)hh[6], (short)hh[7]};
        __syncthreads();
        bf16x8 af[4], bfr[2];
        #pragma unroll
        for (int mi = 0; mi < 4; mi++)
            af[mi] = *(const bf16x8*)&As[(wrb + mi * 16 + lo) * 40 + g * 8];
        #pragma unroll
        for (int ni = 0; ni < 2; ni++)
            bfr[ni] = *(const bf16x8*)&Bs[(wcb + ni * 16 + lo) * 40 + g * 8];
        #pragma unroll
        for (int mi = 0; mi < 4; mi++)
            #pragma unroll
            for (int ni = 0; ni < 2; ni++)
                acc[mi][ni] = __builtin_amdgcn_mfma_f32_16x16x32_bf16(af[mi], bfr[ni], acc[mi][ni], 0, 0, 0);
        __syncthreads();
    }
    #pragma unroll
    for (int mi = 0; mi < 4; mi++)
        #pragma unroll
        for (int r = 0; r < 4; r++) {
            int slot = t0 + wrb + mi * 16 + g * 4 + r;
            if (slot < ce) {
                int tok = toklist[e * SEQ + slot];
                float wt = tokw[e * SEQ + slot];
                #pragma unroll
                for (int ni = 0; ni < 2; ni++)
                    atomicAdd(&out[(size_t)tok * H_DIM + c0 + wcb + ni * 16 + lo],
                              wt * acc[mi][ni][r]);
            }
        }
}

// ---------------------------------------------------------------- launch
extern "C" void kernel_launch(void* const* d_in, const int* in_sizes, int n_in,
                              void* d_out, int out_size, void* d_ws, size_t ws_size,
                              hipStream_t stream) {
    const float* hidden     = (const float*)d_in[0];
    const int*   positions  = (const int*)d_in[1];
    const float* in_norm_w  = (const float*)d_in[2];
    const float* post_norm_w= (const float*)d_in[3];
    const float* qkv_w      = (const float*)d_in[4];
    const float* o_w        = (const float*)d_in[5];
    const float* gate_w     = (const float*)d_in[6];
    const float* gate_bias  = (const float*)d_in[7];
    const float* gate_up_w  = (const float*)d_in[8];
    const float* down_w     = (const float*)d_in[9];
    float* out = (float*)d_out;

    float* ws   = (float*)d_ws;
    float* qkv  = ws;                                  // 1024*3072 f32
    float* h2   = qkv + (size_t)SEQ * QKV_N;           // 1024*2048 f32
    float* x    = h2  + (size_t)SEQ * H_DIM;           // 1024*2048 f32
    float* tokw = x   + (size_t)SEQ * H_DIM;           // 16*1024
    int* toklist = (int*)(tokw + NE * SEQ);            // 16*1024
    int* cnt  = toklist + NE * SEQ;                    // 16
    int* base = cnt + NE;                              // 16
    unsigned short* hb = (unsigned short*)(base + NE); // 1024*2048 bf16
    unsigned short* ob = hb + (size_t)SEQ * H_DIM;     // 1024*2048
    unsigned short* xb = ob + (size_t)SEQ * H_DIM;     // 1024*2048
    unsigned short* act = xb + (size_t)SEQ * H_DIM;    // 4096*1024
    unsigned short* Qb = act + (size_t)4 * SEQ * DFF;  // 16*1024*128
    unsigned short* Kb = Qb + (size_t)NH * SEQ * HD;   // 4*1024*128
    unsigned short* Vt = Kb + (size_t)NKV * SEQ * HD;  // 4*128*1024

    // 1. pre-attention RMSNorm -> bf16
    rmsnorm_dual<<<SEQ, 256, 0, stream>>>(hidden, in_norm_w, nullptr, hb);
    // 2. qkv projection (bf16 MFMA)
    gemm_bf16<<<dim3(QKV_N / 128, SEQ / 128), 256, 0, stream>>>(hb, qkv_w, qkv, nullptr, nullptr,
                                                                SEQ, QKV_N, H_DIM);
    // 3. pack: RoPE+bf16 Q/K, transpose+bf16 V
    pack_qk<<<dim3(SEQ, NH + NKV), 128, 0, stream>>>(qkv, positions, Qb, Kb);
    pack_vt<<<dim3(SEQ / 64, HD / 64, NKV), 256, 0, stream>>>(qkv, Vt);
    // 4. flash attention (bf16 MFMA) -> ob bf16
    attn_mfma<<<dim3(SEQ / 16, NH), 64, 0, stream>>>(Qb, Kb, Vt, ob);
    // 5. o projection + residual -> h2 and d_out
    gemm_bf16<<<dim3(H_DIM / 128, SEQ / 128), 256, 0, stream>>>(ob, o_w, h2, out, hidden,
                                                                SEQ, H_DIM, H_DIM);
    // 6. post-attention RMSNorm -> x (f32 for router) + xb (bf16 for MoE)
    rmsnorm_dual<<<SEQ, 256, 0, stream>>>(h2, post_norm_w, x, xb);
    // 7. router
    hipMemsetAsync(cnt, 0, NE * sizeof(int), stream);
    router_kernel<<<SEQ, 256, 0, stream>>>(x, gate_w, gate_bias, toklist, tokw, cnt);
    prefix_kernel<<<1, 64, 0, stream>>>(cnt, base);
    // 8. MoE
    moe_gemm1_mfma<<<dim3(DFF / 64, SEQ / 128, NE), 256, 0, stream>>>(xb, gate_up_w, toklist, cnt, base, act);
    moe_gemm2_mfma<<<dim3(H_DIM / 64, SEQ / 128, NE), 256, 0, stream>>>(act, down_w, toklist, tokw, cnt, base, out);
}

// Round 4
// 556.688 us; speedup vs baseline: 4.4549x; 1.0383x over previous
//
#include <hip/hip_runtime.h>
#include <hip/hip_bf16.h>
#include <math.h>

#define H_DIM   2048
#define NH      16
#define NKV     4
#define HD      128
#define NE      16
#define TOPK    4
#define DFF     1024
#define NG      4
#define SEQ     1024
#define QKV_N   3072          // (NH + 2*NKV)*HD
#define EPS_RMS 1e-6f
#define THETA   1000000.0f

typedef __attribute__((ext_vector_type(8))) short bf16x8;
typedef __attribute__((ext_vector_type(4))) short s16x4;
typedef __attribute__((ext_vector_type(4))) float f32x4;

__device__ inline unsigned short f2bf(float x) {
    unsigned u = __builtin_bit_cast(unsigned, x);
    unsigned r = (u + 0x7FFFu + ((u >> 16) & 1u)) >> 16;
    return (unsigned short)r;
}

// ---------------------------------------------------------------- RMSNorm (f32 in, optional f32 + bf16 out)
__global__ __launch_bounds__(256) void rmsnorm_dual(const float* __restrict__ in,
                                                    const float* __restrict__ w,
                                                    float* __restrict__ outf,
                                                    unsigned short* __restrict__ outb) {
    int t = blockIdx.x;
    const float* xt = in + (size_t)t * H_DIM;
    float ss = 0.f;
    for (int d = threadIdx.x * 4; d < H_DIM; d += 1024) {
        float4 v = *reinterpret_cast<const float4*>(xt + d);
        ss += v.x * v.x + v.y * v.y + v.z * v.z + v.w * v.w;
    }
    for (int off = 1; off < 64; off <<= 1) ss += __shfl_xor(ss, off);
    __shared__ float red[4];
    __shared__ float srms;
    if ((threadIdx.x & 63) == 0) red[threadIdx.x >> 6] = ss;
    __syncthreads();
    if (threadIdx.x == 0)
        srms = rsqrtf((red[0] + red[1] + red[2] + red[3]) * (1.f / H_DIM) + EPS_RMS);
    __syncthreads();
    float r = srms;
    for (int d = threadIdx.x * 4; d < H_DIM; d += 1024) {
        float4 v  = *reinterpret_cast<const float4*>(xt + d);
        float4 wv = *reinterpret_cast<const float4*>(w + d);
        float4 ov;
        ov.x = v.x * r * wv.x; ov.y = v.y * r * wv.y;
        ov.z = v.z * r * wv.z; ov.w = v.w * r * wv.w;
        if (outf) *reinterpret_cast<float4*>(outf + (size_t)t * H_DIM + d) = ov;
        if (outb) {
            s16x4 bv = (s16x4){(short)f2bf(ov.x), (short)f2bf(ov.y),
                               (short)f2bf(ov.z), (short)f2bf(ov.w)};
            *reinterpret_cast<s16x4*>(outb + (size_t)t * H_DIM + d) = bv;
        }
    }
}

// ---------------------------------------------------------------- qkv GEMM with fused RoPE + bf16 pack
// A(bf16)[1024][2048] @ B(f32)[2048][3072]. BM=128, BN=128 (=1 head), BK=32.
// 4 waves stacked in M (wave = 32 rows x 128 cols) so RoPE pairs (d, d+64) are in-lane.
__global__ __launch_bounds__(256) void gemm_qkv_rope(const unsigned short* __restrict__ A,
                                                     const float* __restrict__ B,
                                                     const int* __restrict__ positions,
                                                     unsigned short* __restrict__ Qb,
                                                     unsigned short* __restrict__ Kb,
                                                     unsigned short* __restrict__ Vt) {
    __shared__ unsigned short As[4][128][8];   // [kg][row][k&7]
    __shared__ unsigned short Bs[4][128][8];   // [kg][col][k&7]
    int xb = blockIdx.x;                       // 0..23: 0-15 Q heads, 16-19 K, 20-23 V
    int row0 = blockIdx.y * 128, col0 = xb * 128;
    int t = threadIdx.x;
    int w = t >> 6, lane = t & 63, lo = lane & 15, g = lane >> 4;
    int wr = w * 32;
    f32x4 acc[2][8];
    #pragma unroll
    for (int mi = 0; mi < 2; mi++)
        #pragma unroll
        for (int ni = 0; ni < 8; ni++) acc[mi][ni] = (f32x4){0.f, 0.f, 0.f, 0.f};
    int ar = t >> 1, akg = (t & 1) * 2;
    int bc = t & 127, bkg = (t >> 7) * 2;
    for (int k0 = 0; k0 < H_DIM; k0 += 32) {
        const unsigned short* ga = A + (size_t)(row0 + ar) * H_DIM + k0 + akg * 8;
        bf16x8 a0 = *(const bf16x8*)ga;
        bf16x8 a1 = *(const bf16x8*)(ga + 8);
        *(bf16x8*)As[akg][ar] = a0;
        *(bf16x8*)As[akg + 1][ar] = a1;
        const float* gb = B + (size_t)(k0 + bkg * 8) * QKV_N + col0 + bc;
        bf16x8 b0, b1;
        #pragma unroll
        for (int j = 0; j < 8; j++) b0[j] = (short)f2bf(gb[(size_t)j * QKV_N]);
        #pragma unroll
        for (int j = 0; j < 8; j++) b1[j] = (short)f2bf(gb[(size_t)(j + 8) * QKV_N]);
        *(bf16x8*)Bs[bkg][bc] = b0;
        *(bf16x8*)Bs[bkg + 1][bc] = b1;
        __syncthreads();
        bf16x8 af[2], bfr[8];
        #pragma unroll
        for (int mi = 0; mi < 2; mi++) af[mi] = *(const bf16x8*)As[g][wr + mi * 16 + lo];
        #pragma unroll
        for (int ni = 0; ni < 8; ni++) bfr[ni] = *(const bf16x8*)Bs[g][ni * 16 + lo];
        #pragma unroll
        for (int mi = 0; mi < 2; mi++)
            #pragma unroll
            for (int ni = 0; ni < 8; ni++)
                acc[mi][ni] = __builtin_amdgcn_mfma_f32_16x16x32_bf16(af[mi], bfr[ni], acc[mi][ni], 0, 0, 0);
        __syncthreads();
    }
    if (xb < NH + NKV) {
        // ---- Q or K head: RoPE, (Q scaled), write [h][t][d]
        bool isQ = (xb < NH);
        unsigned short* dst = isQ ? (Qb + (size_t)xb * SEQ * HD)
                                  : (Kb + (size_t)(xb - NH) * SEQ * HD);
        float qs = isQ ? 0.08838834764831845f : 1.0f;
        float invf[4];
        #pragma unroll
        for (int ni = 0; ni < 4; ni++)
            invf[ni] = __powf(THETA, -(float)(ni * 16 + lo) * (1.0f / 64.0f));
        #pragma unroll
        for (int mi = 0; mi < 2; mi++)
            #pragma unroll
            for (int r = 0; r < 4; r++) {
                int tok = row0 + wr + mi * 16 + g * 4 + r;
                float pos = (float)positions[tok];
                #pragma unroll
                for (int ni = 0; ni < 4; ni++) {
                    float s, c;
                    __sincosf(pos * invf[ni], &s, &c);
                    float x1 = acc[mi][ni][r], x2 = acc[mi][ni + 4][r];
                    int d = ni * 16 + lo;
                    dst[(size_t)tok * HD + d]      = f2bf((x1 * c - x2 * s) * qs);
                    dst[(size_t)tok * HD + d + 64] = f2bf((x2 * c + x1 * s) * qs);
                }
            }
    } else {
        // ---- V head: write transposed Vt[kvh][d][t], 4 consecutive tokens packed
        int kvh = xb - (NH + NKV);
        #pragma unroll
        for (int mi = 0; mi < 2; mi++)
            #pragma unroll
            for (int ni = 0; ni < 8; ni++) {
                int tok0 = row0 + wr + mi * 16 + g * 4;
                int d = ni * 16 + lo;
                ushort4 v4;
                v4.x = f2bf(acc[mi][ni][0]);
                v4.y = f2bf(acc[mi][ni][1]);
                v4.z = f2bf(acc[mi][ni][2]);
                v4.w = f2bf(acc[mi][ni][3]);
                *reinterpret_cast<ushort4*>(Vt + ((size_t)kvh * HD + d) * SEQ + tok0) = v4;
            }
    }
}

// ---------------------------------------------------------------- generic bf16-MFMA GEMM (o-proj)
// C[M,N](f32) = A(bf16)[M,K] @ B(f32)[K,N] (+R), optional dup to C2. BM=BN=128, BK=32.
__global__ __launch_bounds__(256) void gemm_bf16(const unsigned short* __restrict__ A,
                                                 const float* __restrict__ B,
                                                 float* __restrict__ C,
                                                 float* __restrict__ C2,
                                                 const float* __restrict__ R,
                                                 int M, int N, int K) {
    __shared__ unsigned short As[4][128][8];
    __shared__ unsigned short Bs[4][128][8];
    int row0 = blockIdx.y * 128, col0 = blockIdx.x * 128;
    int t = threadIdx.x;
    int w = t >> 6, lane = t & 63, lo = lane & 15, g = lane >> 4;
    int wr = (w >> 1) * 64, wc = (w & 1) * 64;
    f32x4 acc[4][4];
    #pragma unroll
    for (int mi = 0; mi < 4; mi++)
        #pragma unroll
        for (int ni = 0; ni < 4; ni++) acc[mi][ni] = (f32x4){0.f, 0.f, 0.f, 0.f};
    int ar = t >> 1, akg = (t & 1) * 2;
    int bc = t & 127, bkg = (t >> 7) * 2;
    for (int k0 = 0; k0 < K; k0 += 32) {
        const unsigned short* ga = A + (size_t)(row0 + ar) * K + k0 + akg * 8;
        bf16x8 a0 = *(const bf16x8*)ga;
        bf16x8 a1 = *(const bf16x8*)(ga + 8);
        *(bf16x8*)As[akg][ar] = a0;
        *(bf16x8*)As[akg + 1][ar] = a1;
        const float* gb = B + (size_t)(k0 + bkg * 8) * N + col0 + bc;
        bf16x8 b0, b1;
        #pragma unroll
        for (int j = 0; j < 8; j++) b0[j] = (short)f2bf(gb[(size_t)j * N]);
        #pragma unroll
        for (int j = 0; j < 8; j++) b1[j] = (short)f2bf(gb[(size_t)(j + 8) * N]);
        *(bf16x8*)Bs[bkg][bc] = b0;
        *(bf16x8*)Bs[bkg + 1][bc] = b1;
        __syncthreads();
        bf16x8 af[4], bfr[4];
        #pragma unroll
        for (int mi = 0; mi < 4; mi++) af[mi] = *(const bf16x8*)As[g][wr + mi * 16 + lo];
        #pragma unroll
        for (int ni = 0; ni < 4; ni++) bfr[ni] = *(const bf16x8*)Bs[g][wc + ni * 16 + lo];
        #pragma unroll
        for (int mi = 0; mi < 4; mi++)
            #pragma unroll
            for (int ni = 0; ni < 4; ni++)
                acc[mi][ni] = __builtin_amdgcn_mfma_f32_16x16x32_bf16(af[mi], bfr[ni], acc[mi][ni], 0, 0, 0);
        __syncthreads();
    }
    #pragma unroll
    for (int mi = 0; mi < 4; mi++)
        #pragma unroll
        for (int ni = 0; ni < 4; ni++)
            #pragma unroll
            for (int r = 0; r < 4; r++) {
                int row = row0 + wr + mi * 16 + g * 4 + r;
                int col = col0 + wc + ni * 16 + lo;
                size_t idx = (size_t)row * N + col;
                float v = acc[mi][ni][r];
                if (R)  v += R[idx];
                C[idx] = v;
                if (C2) C2[idx] = v;
            }
}

// ---------------------------------------------------------------- flash attention, 1 wave / 16 q-rows, bf16 out
__global__ __launch_bounds__(64) void attn_mfma(const unsigned short* __restrict__ Qb,
                                                const unsigned short* __restrict__ Kb,
                                                const unsigned short* __restrict__ Vt,
                                                unsigned short* __restrict__ ob) {
    int qt = blockIdx.x;
    int h  = blockIdx.y;
    int kvh = h >> 2;
    int q0 = qt * 16;
    int l = threadIdx.x;
    int lo = l & 15, g = l >> 4;

    __shared__ alignas(16) unsigned short pbuf[16][40];

    bf16x8 qf[4];
    const unsigned short* qp = Qb + ((size_t)h * SEQ + q0 + lo) * HD + g * 8;
    #pragma unroll
    for (int ks = 0; ks < 4; ks++)
        qf[ks] = *(const bf16x8*)(qp + ks * 32);

    f32x4 accO[8];
    #pragma unroll
    for (int nd = 0; nd < 8; nd++) accO[nd] = (f32x4){0.f, 0.f, 0.f, 0.f};
    float mrun[4], lrun[4];
    #pragma unroll
    for (int r = 0; r < 4; r++) { mrun[r] = -INFINITY; lrun[r] = 0.f; }

    int nc = (q0 + 16 + 31) / 32;
    for (int ch = 0; ch < nc; ch++) {
        int kv0 = ch * 32;
        f32x4 accS[2];
        accS[0] = (f32x4){0.f, 0.f, 0.f, 0.f};
        accS[1] = (f32x4){0.f, 0.f, 0.f, 0.f};
        const unsigned short* kp = Kb + ((size_t)kvh * SEQ + kv0 + lo) * HD + g * 8;
        #pragma unroll
        for (int n = 0; n < 2; n++) {
            const unsigned short* kpn = kp + (size_t)n * 16 * HD;
            #pragma unroll
            for (int ks = 0; ks < 4; ks++) {
                bf16x8 kf = *(const bf16x8*)(kpn + ks * 32);
                accS[n] = __builtin_amdgcn_mfma_f32_16x16x32_bf16(qf[ks], kf, accS[n], 0, 0, 0);
            }
        }
        if (ch == nc - 1) {
            #pragma unroll
            for (int n = 0; n < 2; n++)
                #pragma unroll
                for (int r = 0; r < 4; r++) {
                    int kv = kv0 + n * 16 + lo;
                    int q  = q0 + g * 4 + r;
                    if (kv > q) accS[n][r] = -1e30f;
                }
        }
        float mt[4], fac[4];
        #pragma unroll
        for (int r = 0; r < 4; r++) {
            float m = fmaxf(accS[0][r], accS[1][r]);
            #pragma unroll
            for (int off = 1; off < 16; off <<= 1) m = fmaxf(m, __shfl_xor(m, off));
            mt[r] = fmaxf(mrun[r], m);
            fac[r] = __expf(mrun[r] - mt[r]);
        }
        float psum[4] = {0.f, 0.f, 0.f, 0.f};
        #pragma unroll
        for (int n = 0; n < 2; n++)
            #pragma unroll
            for (int r = 0; r < 4; r++) {
                float p = __expf(accS[n][r] - mt[r]);
                psum[r] += p;
                pbuf[g * 4 + r][n * 16 + lo] = f2bf(p);
            }
        #pragma unroll
        for (int r = 0; r < 4; r++) {
            float s = psum[r];
            #pragma unroll
            for (int off = 1; off < 16; off <<= 1) s += __shfl_xor(s, off);
            lrun[r] = lrun[r] * fac[r] + s;
            mrun[r] = mt[r];
        }
        #pragma unroll
        for (int nd = 0; nd < 8; nd++)
            #pragma unroll
            for (int r = 0; r < 4; r++) accO[nd][r] *= fac[r];
        __builtin_amdgcn_sched_barrier(0);
        bf16x8 pf = *(const bf16x8*)(&pbuf[lo][g * 8]);
        const unsigned short* vp = Vt + ((size_t)kvh * HD + lo) * SEQ + kv0 + g * 8;
        #pragma unroll
        for (int nd = 0; nd < 8; nd++) {
            bf16x8 vf = *(const bf16x8*)(vp + (size_t)nd * 16 * SEQ);
            accO[nd] = __builtin_amdgcn_mfma_f32_16x16x32_bf16(pf, vf, accO[nd], 0, 0, 0);
        }
        __builtin_amdgcn_sched_barrier(0);
    }
    float inv[4];
    #pragma unroll
    for (int r = 0; r < 4; r++) inv[r] = 1.0f / lrun[r];
    #pragma unroll
    for (int nd = 0; nd < 8; nd++)
        #pragma unroll
        for (int r = 0; r < 4; r++)
            ob[(size_t)(q0 + g * 4 + r) * H_DIM + h * HD + nd * 16 + lo] = f2bf(accO[nd][r] * inv[r]);
}

// ---------------------------------------------------------------- router
__global__ __launch_bounds__(256) void router_kernel(const float* __restrict__ x,
                                                     const float* __restrict__ gate_w,
                                                     const float* __restrict__ gate_bias,
                                                     int* __restrict__ toklist,
                                                     float* __restrict__ tokw,
                                                     int* __restrict__ cnt) {
    int t = blockIdx.x;
    const float* xt = x + (size_t)t * H_DIM;
    __shared__ float logits[NE];
    __shared__ float red[4];
    for (int e = 0; e < NE; e++) {
        float p = 0.f;
        for (int d = threadIdx.x; d < H_DIM; d += 256) p += xt[d] * gate_w[(size_t)e * H_DIM + d];
        for (int off = 1; off < 64; off <<= 1) p += __shfl_xor(p, off);
        if ((threadIdx.x & 63) == 0) red[threadIdx.x >> 6] = p;
        __syncthreads();
        if (threadIdx.x == 0) logits[e] = red[0] + red[1] + red[2] + red[3];
        __syncthreads();
    }
    if (threadIdx.x == 0) {
        float sig[NE], sb[NE];
        for (int e = 0; e < NE; e++) {
            sig[e] = 1.f / (1.f + expf(-logits[e]));
            sb[e] = sig[e] + gate_bias[e];
        }
        float gs[NG];
        for (int g = 0; g < NG; g++) {
            float m1 = -1e30f, m2 = -1e30f;
            for (int i = 0; i < 4; i++) {
                float v = sb[g * 4 + i];
                if (v > m1) { m2 = m1; m1 = v; } else if (v > m2) m2 = v;
            }
            gs[g] = m1 + m2;
        }
        int g1 = 0;
        for (int g = 1; g < NG; g++) if (gs[g] > gs[g1]) g1 = g;
        int g2 = -1;
        for (int g = 0; g < NG; g++) {
            if (g == g1) continue;
            if (g2 < 0 || gs[g] > gs[g2]) g2 = g;
        }
        bool allowed[NE], used[NE];
        for (int e = 0; e < NE; e++) { int g = e >> 2; allowed[e] = (g == g1 || g == g2); used[e] = false; }
        int sel[TOPK]; float wsel[TOPK]; float wsum = 0.f;
        for (int k = 0; k < TOPK; k++) {
            int best = -1; float bv = -1e30f;
            for (int e = 0; e < NE; e++) {
                if (!allowed[e] || used[e]) continue;
                if (best < 0 || sb[e] > bv) { best = e; bv = sb[e]; }
            }
            used[best] = true; sel[k] = best; wsel[k] = sig[best]; wsum += sig[best];
        }
        float invs = 1.f / (wsum + 1e-20f);
        for (int k = 0; k < TOPK; k++) {
            int e = sel[k];
            int slot = atomicAdd(&cnt[e], 1);
            toklist[e * SEQ + slot] = t;
            tokw[e * SEQ + slot] = wsel[k] * invs;
        }
    }
}

__global__ void prefix_kernel(const int* __restrict__ cnt, int* __restrict__ base) {
    if (threadIdx.x == 0) {
        int s = 0;
        for (int e = 0; e < NE; e++) { base[e] = s; s += cnt[e]; }
    }
}

// ---------------------------------------------------------------- MoE GEMM1 (MFMA): act = silu(x@G)*(x@U), bf16 out
// BM=128, BN=64 (G and U each), BK=32. grid (DFF/64, SEQ/128, NE)
__global__ __launch_bounds__(256) void moe_gemm1_mfma(const unsigned short* __restrict__ xb,
                                                      const float* __restrict__ gup,
                                                      const int* __restrict__ toklist,
                                                      const int* __restrict__ cnt,
                                                      const int* __restrict__ base,
                                                      unsigned short* __restrict__ act) {
    int e = blockIdx.z;
    int ce = cnt[e];
    int t0 = blockIdx.y * 128;
    if (t0 >= ce) return;
    int f0 = blockIdx.x * 64;
    __shared__ unsigned short As[4][128][8];
    __shared__ unsigned short BsG[4][64][8];
    __shared__ unsigned short BsU[4][64][8];
    __shared__ int toks[128];
    int t = threadIdx.x;
    if (t < 128) { int s = t0 + t; toks[t] = toklist[e * SEQ + (s < ce ? s : 0)]; }
    __syncthreads();
    int w = t >> 6, lane = t & 63, lo = lane & 15, g = lane >> 4;
    int wrb = (w >> 1) * 64, wcb = (w & 1) * 32;
    f32x4 accG[4][2], accU[4][2];
    #pragma unroll
    for (int mi = 0; mi < 4; mi++)
        #pragma unroll
        for (int ni = 0; ni < 2; ni++) {
            accG[mi][ni] = (f32x4){0.f, 0.f, 0.f, 0.f};
            accU[mi][ni] = (f32x4){0.f, 0.f, 0.f, 0.f};
        }
    int ar = t >> 1, akg = (t & 1) * 2;
    int bc = t & 63, bkg = t >> 6;
    const float* W = gup + (size_t)e * H_DIM * (2 * DFF);
    for (int k0 = 0; k0 < H_DIM; k0 += 32) {
        const unsigned short* ga = xb + (size_t)toks[ar] * H_DIM + k0 + akg * 8;
        bf16x8 a0 = *(const bf16x8*)ga;
        bf16x8 a1 = *(const bf16x8*)(ga + 8);
        *(bf16x8*)As[akg][ar] = a0;
        *(bf16x8*)As[akg + 1][ar] = a1;
        const float* gw = W + (size_t)(k0 + bkg * 8) * (2 * DFF) + f0 + bc;
        bf16x8 bg_, bu_;
        #pragma unroll
        for (int j = 0; j < 8; j++) {
            bg_[j] = (short)f2bf(gw[(size_t)j * (2 * DFF)]);
            bu_[j] = (short)f2bf(gw[(size_t)j * (2 * DFF) + DFF]);
        }
        *(bf16x8*)BsG[bkg][bc] = bg_;
        *(bf16x8*)BsU[bkg][bc] = bu_;
        __syncthreads();
        bf16x8 af[4], bg[2], bu[2];
        #pragma unroll
        for (int mi = 0; mi < 4; mi++) af[mi] = *(const bf16x8*)As[g][wrb + mi * 16 + lo];
        #pragma unroll
        for (int ni = 0; ni < 2; ni++) {
            bg[ni] = *(const bf16x8*)BsG[g][wcb + ni * 16 + lo];
            bu[ni] = *(const bf16x8*)BsU[g][wcb + ni * 16 + lo];
        }
        #pragma unroll
        for (int mi = 0; mi < 4; mi++)
            #pragma unroll
            for (int ni = 0; ni < 2; ni++) {
                accG[mi][ni] = __builtin_amdgcn_mfma_f32_16x16x32_bf16(af[mi], bg[ni], accG[mi][ni], 0, 0, 0);
                accU[mi][ni] = __builtin_amdgcn_mfma_f32_16x16x32_bf16(af[mi], bu[ni], accU[mi][ni], 0, 0, 0);
            }
        __syncthreads();
    }
    int b = base[e];
    #pragma unroll
    for (int mi = 0; mi < 4; mi++)
        #pragma unroll
        for (int ni = 0; ni < 2; ni++)
            #pragma unroll
            for (int r = 0; r < 4; r++) {
                int slot = t0 + wrb + mi * 16 + g * 4 + r;
                if (slot < ce) {
                    float gv = accG[mi][ni][r], uv = accU[mi][ni][r];
                    float a = (gv / (1.f + __expf(-gv))) * uv;
                    act[(size_t)(b + slot) * DFF + f0 + wcb + ni * 16 + lo] = f2bf(a);
                }
            }
}

// ---------------------------------------------------------------- MoE GEMM2 (MFMA): out += w * (act @ down)
// BM=128, BN=64, BK=32. grid (H_DIM/64, SEQ/128, NE)
__global__ __launch_bounds__(256) void moe_gemm2_mfma(const unsigned short* __restrict__ act,
                                                      const float* __restrict__ down,
                                                      const int* __restrict__ toklist,
                                                      const float* __restrict__ tokw,
                                                      const int* __restrict__ cnt,
                                                      const int* __restrict__ base,
                                                      float* __restrict__ out) {
    int e = blockIdx.z;
    int ce = cnt[e];
    int t0 = blockIdx.y * 128;
    if (t0 >= ce) return;
    int c0 = blockIdx.x * 64;
    __shared__ unsigned short As[4][128][8];
    __shared__ unsigned short Bs[4][64][8];
    int t = threadIdx.x;
    int w = t >> 6, lane = t & 63, lo = lane & 15, g = lane >> 4;
    int wrb = (w >> 1) * 64, wcb = (w & 1) * 32;
    int b = base[e];
    f32x4 acc[4][2];
    #pragma unroll
    for (int mi = 0; mi < 4; mi++)
        #pragma unroll
        for (int ni = 0; ni < 2; ni++) acc[mi][ni] = (f32x4){0.f, 0.f, 0.f, 0.f};
    int ar = t >> 1, akg = (t & 1) * 2;
    int bc = t & 63, bkg = t >> 6;
    const float* W = down + (size_t)e * DFF * H_DIM;
    for (int k0 = 0; k0 < DFF; k0 += 32) {
        int slot = t0 + ar;
        int arow = b + (slot < ce ? slot : t0);
        const unsigned short* ga = act + (size_t)arow * DFF + k0 + akg * 8;
        bf16x8 a0 = *(const bf16x8*)ga;
        bf16x8 a1 = *(const bf16x8*)(ga + 8);
        *(bf16x8*)As[akg][ar] = a0;
        *(bf16x8*)As[akg + 1][ar] = a1;
        const float* gw = W + (size_t)(k0 + bkg * 8) * H_DIM + c0 + bc;
        bf16x8 b0;
        #pragma unroll
        for (int j = 0; j < 8; j++) b0[j] = (short)f2bf(gw[(size_t)j * H_DIM]);
        *(bf16x8*)Bs[bkg][bc] = b0;
        __syncthreads();
        bf16x8 af[4], bfr[2];
        #pragma unroll
        for (int mi = 0; mi < 4; mi++) af[mi] = *(const bf16x8*)As[g][wrb + mi * 16 + lo];
        #pragma unroll
        for (int ni = 0; ni < 2; ni++) bfr[ni] = *(const bf16x8*)Bs[g][wcb + ni * 16 + lo];
        #pragma unroll
        for (int mi = 0; mi < 4; mi++)
            #pragma unroll
            for (int ni = 0; ni < 2; ni++)
                acc[mi][ni] = __builtin_amdgcn_mfma_f32_16x16x32_bf16(af[mi], bfr[ni], acc[mi][ni], 0, 0, 0);
        __syncthreads();
    }
    #pragma unroll
    for (int mi = 0; mi < 4; mi++)
        #pragma unroll
        for (int r = 0; r < 4; r++) {
            int slot = t0 + wrb + mi * 16 + g * 4 + r;
            if (slot < ce) {
                int tok = toklist[e * SEQ + slot];
                float wt = tokw[e * SEQ + slot];
                #pragma unroll
                for (int ni = 0; ni < 2; ni++)
                    atomicAdd(&out[(size_t)tok * H_DIM + c0 + wcb + ni * 16 + lo],
                              wt * acc[mi][ni][r]);
            }
        }
}

// ---------------------------------------------------------------- launch
extern "C" void kernel_launch(void* const* d_in, const int* in_sizes, int n_in,
                              void* d_out, int out_size, void* d_ws, size_t ws_size,
                              hipStream_t stream) {
    const float* hidden     = (const float*)d_in[0];
    const int*   positions  = (const int*)d_in[1];
    const float* in_norm_w  = (const float*)d_in[2];
    const float* post_norm_w= (const float*)d_in[3];
    const float* qkv_w      = (const float*)d_in[4];
    const float* o_w        = (const float*)d_in[5];
    const float* gate_w     = (const float*)d_in[6];
    const float* gate_bias  = (const float*)d_in[7];
    const float* gate_up_w  = (const float*)d_in[8];
    const float* down_w     = (const float*)d_in[9];
    float* out = (float*)d_out;

    float* ws   = (float*)d_ws;
    float* h2   = ws;                                  // 1024*2048 f32
    float* x    = h2  + (size_t)SEQ * H_DIM;           // 1024*2048 f32
    float* tokw = x   + (size_t)SEQ * H_DIM;           // 16*1024
    int* toklist = (int*)(tokw + NE * SEQ);            // 16*1024
    int* cnt  = toklist + NE * SEQ;                    // 16
    int* base = cnt + NE;                              // 16
    unsigned short* hb = (unsigned short*)(base + NE); // 1024*2048 bf16
    unsigned short* ob = hb + (size_t)SEQ * H_DIM;     // 1024*2048
    unsigned short* xbuf = ob + (size_t)SEQ * H_DIM;   // 1024*2048
    unsigned short* act = xbuf + (size_t)SEQ * H_DIM;  // 4096*1024
    unsigned short* Qb = act + (size_t)4 * SEQ * DFF;  // 16*1024*128
    unsigned short* Kb = Qb + (size_t)NH * SEQ * HD;   // 4*1024*128
    unsigned short* Vt = Kb + (size_t)NKV * SEQ * HD;  // 4*128*1024

    // 1. pre-attention RMSNorm -> bf16
    rmsnorm_dual<<<SEQ, 256, 0, stream>>>(hidden, in_norm_w, nullptr, hb);
    // 2. qkv projection fused with RoPE + bf16/transpose pack
    gemm_qkv_rope<<<dim3(QKV_N / 128, SEQ / 128), 256, 0, stream>>>(hb, qkv_w, positions, Qb, Kb, Vt);
    // 3. flash attention (bf16 MFMA) -> ob bf16
    attn_mfma<<<dim3(SEQ / 16, NH), 64, 0, stream>>>(Qb, Kb, Vt, ob);
    // 4. o projection + residual -> h2 and d_out
    gemm_bf16<<<dim3(H_DIM / 128, SEQ / 128), 256, 0, stream>>>(ob, o_w, h2, out, hidden,
                                                                SEQ, H_DIM, H_DIM);
    // 5. post-attention RMSNorm -> x (f32 for router) + xbuf (bf16 for MoE)
    rmsnorm_dual<<<SEQ, 256, 0, stream>>>(h2, post_norm_w, x, xbuf);
    // 6. router
    hipMemsetAsync(cnt, 0, NE * sizeof(int), stream);
    router_kernel<<<SEQ, 256, 0, stream>>>(x, gate_w, gate_bias, toklist, tokw, cnt);
    prefix_kernel<<<1, 64, 0, stream>>>(cnt, base);
    // 7. MoE
    moe_gemm1_mfma<<<dim3(DFF / 64, SEQ / 128, NE), 256, 0, stream>>>(xbuf, gate_up_w, toklist, cnt, base, act);
    moe_gemm2_mfma<<<dim3(H_DIM / 64, SEQ / 128, NE), 256, 0, stream>>>(act, down_w, toklist, tokw, cnt, base, out);
}